// Round 5
// baseline (1525.312 us; speedup 1.0000x reference)
//
#include <hip/hip_runtime.h>

typedef unsigned short u16;
typedef short bh8 __attribute__((ext_vector_type(8)));
typedef float f32x4 __attribute__((ext_vector_type(4)));

#define NSEQ 8192
#define ALOFF 1048576   // hi->lo element offset for 2MB-hi blocks [16][256][256]
#define KVLOFF 262144   // hi->lo element offset for kv [16][256][64]
#define NSPLIT 8        // split for flash attn3

__device__ __forceinline__ float b2f(u16 u){
  union { unsigned int u32; float f; } v; v.u32 = ((unsigned int)u) << 16; return v.f;
}
__device__ __forceinline__ u16 f2b(float f){
  union { float f; unsigned int u32; } v; v.f = f;
  unsigned int r = (v.u32 + 0x7FFFu + ((v.u32 >> 16) & 1u)) >> 16;
  return (u16)r;
}

// ================= setup: flag + small cvt + weight transposes + zero state =================
__global__ __launch_bounds__(256) void setup_kernel(const void* g, const void* bta, const void* bo,
                                                    const void* cw, const void* wq, const void* wo,
                                                    u16* gb, u16* bb, u16* bob, u16* cwb,
                                                    u16* wqt, u16* wot,
                                                    unsigned* flag, int* bar, float* colsum){
  int f32 = (((const u16*)g)[0] != 0x3F80u);
  long tid = (long)blockIdx.x*256 + threadIdx.x;
  long nth = (long)gridDim.x*256;
  if(tid==0){ *flag = (unsigned)f32; bar[0]=0; bar[1]=0; }
  for(long i=tid;i<4096;i+=nth) colsum[i]=0.f;
  for(long i=tid;i<512;i+=nth) gb[i]  = f32 ? f2b(((const float*)g)[i])   : ((const u16*)g)[i];
  for(long i=tid;i<512;i+=nth) bb[i]  = f32 ? f2b(((const float*)bta)[i]) : ((const u16*)bta)[i];
  for(long i=tid;i<512;i+=nth) bob[i] = f32 ? f2b(((const float*)bo)[i])  : ((const u16*)bo)[i];
  for(long i=tid;i<264;i+=nth) cwb[i] = f32 ? f2b(((const float*)cw)[i])  : ((const u16*)cw)[i];
  for(long i=tid;i<786432;i+=nth){
    long n = i>>9, k = i&511;
    wqt[i] = f32 ? f2b(((const float*)wq)[k*1536+n]) : ((const u16*)wq)[k*1536+n];
  }
  for(long i=tid;i<262144;i+=nth){
    long n = i>>9, k = i&511;
    wot[i] = f32 ? f2b(((const float*)wo)[k*512+n]) : ((const u16*)wo)[k*512+n];
  }
}

// ================= LayerNorm =================
__global__ __launch_bounds__(256) void ln_kernel(const void* xv, const unsigned* flag,
                                                 const u16* g, const u16* bta, u16* xn){
  int f32 = (*flag != 0u);
  long base = (long)blockIdx.x * 512;
  int t = threadIdx.x;
  float v0, v1;
  if(f32){ v0 = ((const float*)xv)[base+t]; v1 = ((const float*)xv)[base+256+t]; }
  else   { v0 = b2f(((const u16*)xv)[base+t]); v1 = b2f(((const u16*)xv)[base+256+t]); }
  float s = v0 + v1, sq = v0*v0 + v1*v1;
  #pragma unroll
  for(int k=1;k<64;k<<=1){ s += __shfl_xor(s,k,64); sq += __shfl_xor(sq,k,64); }
  __shared__ float s4[4], q4[4];
  if((t&63)==0){ s4[t>>6]=s; q4[t>>6]=sq; }
  __syncthreads();
  s = s4[0]+s4[1]+s4[2]+s4[3];
  sq = q4[0]+q4[1]+q4[2]+q4[3];
  float mu = s * (1.f/512.f);
  float var = sq * (1.f/512.f) - mu*mu;
  float inv = rsqrtf(var + 1e-5f);
  xn[base + t]       = f2b((v0-mu)*inv*b2f(g[t])     + b2f(bta[t]));
  xn[base + 256 + t] = f2b((v1-mu)*inv*b2f(g[t+256]) + b2f(bta[t+256]));
}

// ================= 128x128 MFMA GEMM: A[M][K] x Bt[N][K] -> C[M][N] =================
struct G128 {
  const u16 *A, *Bt; u16* C;
  const u16 *bias, *resid;
  const unsigned* oflag;
  int lda, ldb, ldc, ldr, K;
};
__global__ __launch_bounds__(256) void gemm128_kernel(G128 p){
  __shared__ u16 Ah[128][40];
  __shared__ u16 Bh[128][40];
  int t = threadIdx.x;
  int n0 = blockIdx.x*128, m0 = blockIdx.y*128;
  int w = t>>6, lane = t&63, l15 = lane&15, quad = lane>>4;
  int mw = (w>>1)*64, nw = (w&1)*64;
  int r0 = t>>2, c0 = (t&3)*8;
  f32x4 acc[4][4];
  #pragma unroll
  for(int i=0;i<4;i++)
    #pragma unroll
    for(int j=0;j<4;j++)
      #pragma unroll
      for(int k=0;k<4;k++) acc[i][j][k]=0.f;

  for(int kk=0; kk<p.K; kk+=32){
    __syncthreads();
    *(uint4*)&Ah[r0][c0]    = *(const uint4*)(p.A + (long)(m0+r0)*p.lda    + kk + c0);
    *(uint4*)&Ah[r0+64][c0] = *(const uint4*)(p.A + (long)(m0+r0+64)*p.lda + kk + c0);
    *(uint4*)&Bh[r0][c0]    = *(const uint4*)(p.Bt + (long)(n0+r0)*p.ldb    + kk + c0);
    *(uint4*)&Bh[r0+64][c0] = *(const uint4*)(p.Bt + (long)(n0+r0+64)*p.ldb + kk + c0);
    __syncthreads();
    bh8 av[4], bv[4];
    #pragma unroll
    for(int mi=0;mi<4;mi++) av[mi] = *(const bh8*)&Ah[mw + mi*16 + l15][quad*8];
    #pragma unroll
    for(int ni=0;ni<4;ni++) bv[ni] = *(const bh8*)&Bh[nw + ni*16 + l15][quad*8];
    #pragma unroll
    for(int mi=0;mi<4;mi++)
      #pragma unroll
      for(int ni=0;ni<4;ni++)
        acc[mi][ni] = __builtin_amdgcn_mfma_f32_16x16x32_bf16(av[mi], bv[ni], acc[mi][ni], 0,0,0);
  }
  int f32o = p.oflag ? (int)(*p.oflag) : 0;
  #pragma unroll
  for(int mi=0;mi<4;mi++)
    #pragma unroll
    for(int ni=0;ni<4;ni++)
      #pragma unroll
      for(int r=0;r<4;r++){
        int row = m0 + mw + mi*16 + quad*4 + r;
        int col = n0 + nw + ni*16 + l15;
        float v = acc[mi][ni][r];
        if(p.bias)  v += b2f(p.bias[col]);
        if(p.resid) v += b2f(p.resid[(long)row*p.ldr + col]);
        long coff = (long)row*p.ldc + col;
        if(p.oflag){
          if(f32o) ((float*)p.C)[coff] = v; else p.C[coff] = f2b(v);
        } else p.C[coff] = f2b(v);
      }
}

// ================= landmarks (q_l pre-scaled by 0.125) =================
__global__ __launch_bounds__(64) void landmark_kernel(const u16* qkv, u16* ql, u16* kl){
  int m = blockIdx.x, bh = blockIdx.y;
  int b = bh>>3, h = bh&7;
  int d = threadIdx.x;
  long base = ((long)b*NSEQ + (long)m*32)*1536 + h*64 + d;
  float sq=0.f, sk=0.f;
  for(int i=0;i<32;i++){
    sq += b2f(qkv[base + (long)i*1536]);
    sk += b2f(qkv[base + (long)i*1536 + 512]);
  }
  long o = ((long)bh*256 + m)*64 + d;
  ql[o] = f2b(sq * (1.f/32.f) * 0.125f);
  kl[o] = f2b(sk * (1.f/32.f));
}

// ================= fused sim2 + softmax + colsum -> attn2 hilo =================
__global__ __launch_bounds__(256) void sim2_kernel(const u16* ql, const u16* kl,
                                                   u16* ab, float* colsum){
  int mt = blockIdx.x, bh = blockIdx.y;
  __shared__ u16 qlds[64][72];
  __shared__ u16 klds[256][72];
  int t = threadIdx.x, w = t>>6, lane = t&63, l15 = lane&15, quad = lane>>4;
  {
    int r = t>>2, c = (t&3)*16;
    const u16* src = ql + (long)bh*16384 + (long)(mt*64 + r)*64 + c;
    *(uint4*)&qlds[r][c]   = *(const uint4*)src;
    *(uint4*)&qlds[r][c+8] = *(const uint4*)(src+8);
    #pragma unroll
    for(int pss=0; pss<4; pss++){
      int kr = pss*64 + r;
      const u16* ks = kl + (long)bh*16384 + (long)kr*64 + c;
      *(uint4*)&klds[kr][c]   = *(const uint4*)ks;
      *(uint4*)&klds[kr][c+8] = *(const uint4*)(ks+8);
    }
  }
  __syncthreads();
  f32x4 acc[16];
  #pragma unroll
  for(int i=0;i<16;i++)
    #pragma unroll
    for(int j=0;j<4;j++) acc[i][j]=0.f;
  #pragma unroll
  for(int g=0; g<16; g++)
    #pragma unroll
    for(int kk=0; kk<64; kk+=32){
      bh8 a  = *(const bh8*)&qlds[w*16+l15][kk+quad*8];
      bh8 bb = *(const bh8*)&klds[g*16+l15][kk+quad*8];
      acc[g] = __builtin_amdgcn_mfma_f32_16x16x32_bf16(a, bb, acc[g], 0,0,0);
    }
  // row softmax (rows on 16-lane groups)
  #pragma unroll
  for(int r=0;r<4;r++){
    float m = -3.0e38f;
    #pragma unroll
    for(int g=0;g<16;g++) m = fmaxf(m, acc[g][r]);
    #pragma unroll
    for(int k=1;k<16;k<<=1) m = fmaxf(m, __shfl_xor(m,k,16));
    float s = 0.f;
    #pragma unroll
    for(int g=0;g<16;g++){ float e = __expf(acc[g][r]-m); acc[g][r]=e; s+=e; }
    #pragma unroll
    for(int k=1;k<16;k<<=1) s += __shfl_xor(s,k,16);
    float inv = 1.f/s;
    #pragma unroll
    for(int g=0;g<16;g++) acc[g][r] *= inv;
  }
  // store hilo + per-column partial sums
  long bbase = (long)bh*65536;
  #pragma unroll
  for(int g=0;g<16;g++){
    float ps = 0.f;
    #pragma unroll
    for(int r=0;r<4;r++){
      int row = mt*64 + w*16 + quad*4 + r;
      int col = g*16 + l15;
      float pv = acc[g][r];
      u16 h = f2b(pv);
      ab[bbase + (long)row*256 + col] = h;
      ab[ALOFF + bbase + (long)row*256 + col] = f2b(pv - b2f(h));
      ps += pv;
    }
    ps += __shfl_xor(ps, 16);
    ps += __shfl_xor(ps, 32);
    if(quad==0) atomicAdd(&colsum[bh*256 + g*16 + l15], ps);
  }
}

// ================= pinv init: z0 = a^T / colmax  (hilo out) =================
__global__ __launch_bounds__(256) void pinv_init_kernel(const u16* ah, const float* colsum, u16* zh){
  int tile = blockIdx.x, bh = blockIdx.y;
  int tx = tile&3, ty = tile>>2;
  __shared__ u16 th[64][72], tl[64][72];
  __shared__ float red[4];
  int t = threadIdx.x;
  float mc = 0.f;
  for(int i=t;i<4096;i+=256) mc = fmaxf(mc, colsum[i]);
  #pragma unroll
  for(int k=1;k<64;k<<=1) mc = fmaxf(mc, __shfl_xor(mc,k,64));
  if((t&63)==0) red[t>>6]=mc;
  int r = t>>2, c = (t&3)*16;
  const u16* src = ah + (long)bh*65536 + (long)(ty*64 + r)*256 + tx*64 + c;
  *(uint4*)&th[r][c]   = *(const uint4*)src;
  *(uint4*)&th[r][c+8] = *(const uint4*)(src+8);
  *(uint4*)&tl[r][c]   = *(const uint4*)(src+ALOFF);
  *(uint4*)&tl[r][c+8] = *(const uint4*)(src+ALOFF+8);
  __syncthreads();
  float dinv = 1.f/fmaxf(fmaxf(red[0],red[1]), fmaxf(red[2],red[3]));
  u16 oh[16], ol[16];
  #pragma unroll
  for(int jj=0;jj<16;jj++){
    float v = (b2f(th[c+jj][r]) + b2f(tl[c+jj][r])) * dinv;
    u16 h = f2b(v);
    oh[jj] = h; ol[jj] = f2b(v - b2f(h));
  }
  u16* dst = zh + (long)bh*65536 + (long)(tx*64 + r)*256 + ty*64 + c;
  *(uint4*)dst     = *(uint4*)oh;
  *(uint4*)(dst+8) = *(uint4*)(oh+8);
  *(uint4*)(dst+ALOFF)   = *(uint4*)ol;
  *(uint4*)(dst+ALOFF+8) = *(uint4*)(ol+8);
}

// ================= persistent Newton-Schulz (24 steps, device-wide barrier) =================
__device__ __forceinline__ void gbar(int* bar, int phase){
  __syncthreads();
  if(threadIdx.x==0){
    __threadfence();
    int arrived = __hip_atomic_fetch_add(&bar[0], 1, __ATOMIC_ACQ_REL, __HIP_MEMORY_SCOPE_AGENT);
    if(arrived == 255){
      __hip_atomic_store(&bar[0], 0, __ATOMIC_RELAXED, __HIP_MEMORY_SCOPE_AGENT);
      __hip_atomic_store(&bar[1], phase, __ATOMIC_RELEASE, __HIP_MEMORY_SCOPE_AGENT);
    } else {
      while(__hip_atomic_load(&bar[1], __ATOMIC_ACQUIRE, __HIP_MEMORY_SCOPE_AGENT) != phase)
        __builtin_amdgcn_s_sleep(1);
    }
  }
  __syncthreads();
}

__device__ __forceinline__ void ns_step(const u16* A, const u16* B,
                                        u16* Ch, u16* Cl, u16* C2h, u16* C2l,
                                        float alpha, float beta, float alpha2, float beta2,
                                        long boff, int m0, int n0, int t,
                                        u16 (*Ah)[40], u16 (*Al)[40],
                                        u16 (*Bh)[40], u16 (*Bl)[40]){
  int w = t>>6, lane = t&63, l15 = lane&15, quad = lane>>4;
  int ar = t>>2, ac = (t&3)*8;
  int bk = t>>3, bn = (t&7)*8;
  f32x4 acc[4];
  #pragma unroll
  for(int i=0;i<4;i++)
    #pragma unroll
    for(int j=0;j<4;j++) acc[i][j]=0.f;
  for(int kk=0; kk<256; kk+=32){
    __syncthreads();
    *(uint4*)&Ah[ar][ac] = *(const uint4*)(A + boff + (long)(m0+ar)*256 + kk + ac);
    *(uint4*)&Al[ar][ac] = *(const uint4*)(A + ALOFF + boff + (long)(m0+ar)*256 + kk + ac);
    u16 th[8], tl[8];
    *(uint4*)th = *(const uint4*)(B + boff + (long)(kk+bk)*256 + n0 + bn);
    *(uint4*)tl = *(const uint4*)(B + ALOFF + boff + (long)(kk+bk)*256 + n0 + bn);
    #pragma unroll
    for(int j=0;j<8;j++){ Bh[bn+j][bk] = th[j]; Bl[bn+j][bk] = tl[j]; }
    __syncthreads();
    bh8 a  = *(const bh8*)&Ah[w*16+l15][quad*8];
    bh8 al = *(const bh8*)&Al[w*16+l15][quad*8];
    #pragma unroll
    for(int ct=0; ct<4; ct++){
      bh8 b  = *(const bh8*)&Bh[ct*16+l15][quad*8];
      bh8 bl = *(const bh8*)&Bl[ct*16+l15][quad*8];
      acc[ct] = __builtin_amdgcn_mfma_f32_16x16x32_bf16(a,  b,  acc[ct], 0,0,0);
      acc[ct] = __builtin_amdgcn_mfma_f32_16x16x32_bf16(a,  bl, acc[ct], 0,0,0);
      acc[ct] = __builtin_amdgcn_mfma_f32_16x16x32_bf16(al, b,  acc[ct], 0,0,0);
    }
  }
  #pragma unroll
  for(int ct=0; ct<4; ct++)
    #pragma unroll
    for(int r=0;r<4;r++){
      int col = n0 + ct*16 + l15;
      int row = m0 + w*16 + quad*4 + r;
      long coff = boff + (long)row*256 + col;
      float v = acc[ct][r];
      float v1 = alpha*v + ((row==col) ? beta : 0.f);
      u16 h = f2b(v1);
      Ch[coff] = h;
      Cl[coff] = f2b(v1 - b2f(h));
      if(C2h){
        float v2 = alpha2*v + ((row==col) ? beta2 : 0.f);
        u16 h2 = f2b(v2);
        C2h[coff] = h2;
        C2l[coff] = f2b(v2 - b2f(h2));
      }
    }
}

struct NSP { const u16* ab; u16 *zA, *zB, *az, *t1, *t2; int* bar; };
__global__ __launch_bounds__(256) void ns_kernel(NSP p){
  __shared__ u16 Ah[64][40], Al[64][40], Bh[64][40], Bl[64][40];
  int t = threadIdx.x;
  int blk = blockIdx.x;
  long boff = (long)(blk>>4)*65536;
  int m0 = ((blk>>2)&3)*64, n0 = (blk&3)*64;
  u16* zc = p.zA; u16* zn = p.zB;
  int phase = 0;
  for(int it=0; it<6; it++){
    ns_step(p.ab, zc,   p.az, p.az+ALOFF, p.t1, p.t1+ALOFF, 1.f, 0.f, -1.f, 7.f,
            boff, m0, n0, t, Ah, Al, Bh, Bl);
    gbar(p.bar, ++phase);
    ns_step(p.az, p.t1, p.t2, p.t2+ALOFF, 0, 0, -1.f, 15.f, 0.f, 0.f,
            boff, m0, n0, t, Ah, Al, Bh, Bl);
    gbar(p.bar, ++phase);
    ns_step(p.az, p.t2, p.t1, p.t1+ALOFF, 0, 0, -1.f, 13.f, 0.f, 0.f,
            boff, m0, n0, t, Ah, Al, Bh, Bl);
    gbar(p.bar, ++phase);
    ns_step(zc, p.t1,   zn, zn+ALOFF, 0, 0, 0.25f, 0.f, 0.f, 0.f,
            boff, m0, n0, t, Ah, Al, Bh, Bl);
    gbar(p.bar, ++phase);
    u16* tmp = zc; zc = zn; zn = tmp;
  }
}

// ================= W2t = (z @ kv)^T  (hilo in, bf16 out transposed) =================
__global__ __launch_bounds__(256) void w2t_kernel(const u16* z, const u16* kvh, u16* w2t){
  __shared__ u16 Ah[64][40], Al[64][40], Bh[64][40], Bl[64][40];
  int t = threadIdx.x;
  int bh = blockIdx.z;
  int m0 = blockIdx.y*64;
  long za = (long)bh*65536;
  long kb = (long)bh*16384;
  int w = t>>6, lane = t&63, l15 = lane&15, quad = lane>>4;
  int ar = t>>2, ac = (t&3)*8;
  int bk = t>>3, bn = (t&7)*8;
  f32x4 acc[4];
  #pragma unroll
  for(int i=0;i<4;i++)
    #pragma unroll
    for(int j=0;j<4;j++) acc[i][j]=0.f;
  for(int kk=0; kk<256; kk+=32){
    __syncthreads();
    *(uint4*)&Ah[ar][ac] = *(const uint4*)(z + za + (long)(m0+ar)*256 + kk + ac);
    *(uint4*)&Al[ar][ac] = *(const uint4*)(z + ALOFF + za + (long)(m0+ar)*256 + kk + ac);
    u16 th[8], tl[8];
    *(uint4*)th = *(const uint4*)(kvh + kb + (long)(kk+bk)*64 + bn);
    *(uint4*)tl = *(const uint4*)(kvh + KVLOFF + kb + (long)(kk+bk)*64 + bn);
    #pragma unroll
    for(int j=0;j<8;j++){ Bh[bn+j][bk] = th[j]; Bl[bn+j][bk] = tl[j]; }
    __syncthreads();
    bh8 a  = *(const bh8*)&Ah[w*16+l15][quad*8];
    bh8 al = *(const bh8*)&Al[w*16+l15][quad*8];
    #pragma unroll
    for(int ct=0; ct<4; ct++){
      bh8 b  = *(const bh8*)&Bh[ct*16+l15][quad*8];
      bh8 bl = *(const bh8*)&Bl[ct*16+l15][quad*8];
      acc[ct] = __builtin_amdgcn_mfma_f32_16x16x32_bf16(a,  b,  acc[ct], 0,0,0);
      acc[ct] = __builtin_amdgcn_mfma_f32_16x16x32_bf16(a,  bl, acc[ct], 0,0,0);
      acc[ct] = __builtin_amdgcn_mfma_f32_16x16x32_bf16(al, b,  acc[ct], 0,0,0);
    }
  }
  #pragma unroll
  for(int ct=0; ct<4; ct++)
    #pragma unroll
    for(int r=0;r<4;r++){
      int col = ct*16 + l15;             // d
      int row = m0 + w*16 + quad*4 + r;  // landmark j
      w2t[kb + (long)col*256 + row] = f2b(acc[ct][r]);
    }
}

// ================= flash sim3+softmax+@v (split over seq) =================
__global__ __launch_bounds__(256) void attn3f_kernel(const u16* ql, const u16* qkv,
                                                     float* opart, float* mpart, float* lpart){
  int s = blockIdx.x, mt = blockIdx.y, bh = blockIdx.z;
  int b = bh>>3, h = bh&7;
  __shared__ u16 qlds[64][72];
  __shared__ u16 Kh[128][72];
  __shared__ u16 Vt[64][136];
  __shared__ u16 plds[64][136];
  int t = threadIdx.x, w = t>>6, lane = t&63, l15 = lane&15, quad = lane>>4;
  {
    int r = t>>2, c = (t&3)*16;
    const u16* src = ql + (long)bh*16384 + (long)(mt*64 + r)*64 + c;
    *(uint4*)&qlds[r][c]   = *(const uint4*)src;
    *(uint4*)&qlds[r][c+8] = *(const uint4*)(src+8);
  }
  float mrun[4], lrun[4];
  #pragma unroll
  for(int r=0;r<4;r++){ mrun[r] = -3.0e38f; lrun[r] = 0.f; }
  f32x4 O[4];
  #pragma unroll
  for(int i=0;i<4;i++)
    #pragma unroll
    for(int j=0;j<4;j++) O[i][j]=0.f;

  for(int ch=0; ch<8; ch++){
    long n0 = (long)s*1024 + ch*128;
    __syncthreads();
    #pragma unroll
    for(int pss=0; pss<4; pss++){
      int r = pss*32 + (t>>3), c = (t&7)*8;
      const u16* ksrc = qkv + 512 + ((long)b*NSEQ + n0 + r)*1536 + h*64 + c;
      *(uint4*)&Kh[r][c] = *(const uint4*)ksrc;
      u16 tv[8];
      *(uint4*)tv = *(const uint4*)(ksrc + 512);   // v lives 512 past k
      #pragma unroll
      for(int j=0;j<8;j++) Vt[c+j][r] = tv[j];
    }
    __syncthreads();
    // scores 64x128 (wave: 16 rows)
    f32x4 sc[8];
    #pragma unroll
    for(int i=0;i<8;i++)
      #pragma unroll
      for(int j=0;j<4;j++) sc[i][j]=0.f;
    #pragma unroll
    for(int g=0; g<8; g++)
      #pragma unroll
      for(int kk=0; kk<64; kk+=32){
        bh8 a  = *(const bh8*)&qlds[w*16+l15][kk+quad*8];
        bh8 bb = *(const bh8*)&Kh[g*16+l15][kk+quad*8];
        sc[g] = __builtin_amdgcn_mfma_f32_16x16x32_bf16(a, bb, sc[g], 0,0,0);
      }
    // online softmax
    #pragma unroll
    for(int r=0;r<4;r++){
      float cm = -3.0e38f;
      #pragma unroll
      for(int g=0;g<8;g++) cm = fmaxf(cm, sc[g][r]);
      #pragma unroll
      for(int k=1;k<16;k<<=1) cm = fmaxf(cm, __shfl_xor(cm,k,16));
      float nm = fmaxf(mrun[r], cm);
      float alpha = __expf(mrun[r]-nm);
      mrun[r] = nm;
      float psum = 0.f;
      #pragma unroll
      for(int g=0;g<8;g++){ float e = __expf(sc[g][r]-nm); sc[g][r]=e; psum+=e; }
      #pragma unroll
      for(int k=1;k<16;k<<=1) psum += __shfl_xor(psum,k,16);
      lrun[r] = lrun[r]*alpha + psum;
      #pragma unroll
      for(int ct=0;ct<4;ct++) O[ct][r] *= alpha;
    }
    // P -> LDS (wave-private rows)
    #pragma unroll
    for(int g=0;g<8;g++)
      #pragma unroll
      for(int r=0;r<4;r++)
        plds[w*16 + quad*4 + r][g*16 + l15] = f2b(sc[g][r]);
    __syncthreads();
    // O += P @ V
    #pragma unroll
    for(int kk=0; kk<128; kk+=32){
      bh8 a = *(const bh8*)&plds[w*16+l15][kk+quad*8];
      #pragma unroll
      for(int ct=0; ct<4; ct++){
        bh8 bb = *(const bh8*)&Vt[ct*16+l15][kk+quad*8];
        O[ct] = __builtin_amdgcn_mfma_f32_16x16x32_bf16(a, bb, O[ct], 0,0,0);
      }
    }
  }
  long rbase = (long)(s*16 + bh)*256 + mt*64 + w*16;
  #pragma unroll
  for(int ct=0; ct<4; ct++)
    #pragma unroll
    for(int r=0;r<4;r++)
      opart[(rbase + quad*4 + r)*64 + ct*16 + l15] = O[ct][r];
  if(l15==0){
    #pragma unroll
    for(int r=0;r<4;r++){
      mpart[rbase + quad*4 + r] = mrun[r];
      lpart[rbase + quad*4 + r] = lrun[r];
    }
  }
}

// ================= combine flash partials -> kv hilo =================
__global__ __launch_bounds__(256) void kvcomb_kernel(const float* opart, const float* mpart,
                                                     const float* lpart, u16* kvh){
  long i = (long)blockIdx.x*256 + threadIdx.x;  // 0..262143
  int col = (int)(i & 63);
  long rb = i >> 6;                              // bh*256+row
  float M = -3.0e38f;
  #pragma unroll
  for(int s=0;s<NSPLIT;s++) M = fmaxf(M, mpart[(long)s*4096 + rb]);
  float num = 0.f, den = 0.f;
  #pragma unroll
  for(int s=0;s<NSPLIT;s++){
    float e = __expf(mpart[(long)s*4096 + rb] - M);
    den += e * lpart[(long)s*4096 + rb];
    num += e * opart[((long)s*4096 + rb)*64 + col];
  }
  float v = num/den;
  u16 h = f2b(v);
  kvh[i] = h;
  kvh[KVLOFF + i] = f2b(v - b2f(h));
}

// ================= fused attn1 path: oh2 = softmax(0.125*q@kl^T) @ W2 =================
__global__ __launch_bounds__(256) void attn1_kernel(const u16* qkv, const u16* kl,
                                                    const u16* w2t, u16* oh2){
  int bh = blockIdx.y, b = bh>>3, h = bh&7;
  int n0 = blockIdx.x*64;
  __shared__ u16 qlds[64][72];
  __shared__ u16 klds[64][72];
  __shared__ u16 plds[64][264];
  __shared__ u16 w2lds[64][72];
  int t = threadIdx.x, w = t>>6, lane = t&63, l15 = lane&15, quad = lane>>4;
  {
    int r = t>>2, c = (t&3)*16;
    const u16* src = qkv + ((long)b*NSEQ + n0 + r)*1536 + h*64 + c;
    *(uint4*)&qlds[r][c]   = *(const uint4*)src;
    *(uint4*)&qlds[r][c+8] = *(const uint4*)(src+8);
  }
  f32x4 acc[16];
  #pragma unroll
  for(int i=0;i<16;i++)
    #pragma unroll
    for(int j=0;j<4;j++) acc[i][j]=0.f;
  const u16* klb = kl + (long)bh*16384;
  for(int nt=0; nt<4; nt++){
    __syncthreads();
    {
      int r = t>>2, c = (t&3)*16;
      const u16* src = klb + (long)(nt*64 + r)*64 + c;
      *(uint4*)&klds[r][c]   = *(const uint4*)src;
      *(uint4*)&klds[r][c+8] = *(const uint4*)(src+8);
    }
    __syncthreads();
    #pragma unroll
    for(int kk=0; kk<64; kk+=32){
      bh8 a = *(const bh8*)&qlds[w*16+l15][kk+quad*8];
      #pragma unroll
      for(int ct=0; ct<4; ct++){
        bh8 bb = *(const bh8*)&klds[ct*16+l15][kk+quad*8];
        acc[nt*4+ct] = __builtin_amdgcn_mfma_f32_16x16x32_bf16(a, bb, acc[nt*4+ct], 0,0,0);
      }
    }
  }
  float linv[4];
  #pragma unroll
  for(int g=0; g<16; g++)
    #pragma unroll
    for(int r=0;r<4;r++) acc[g][r] *= 0.125f;
  #pragma unroll
  for(int r=0;r<4;r++){
    float m = -3.0e38f;
    #pragma unroll
    for(int g=0;g<16;g++) m = fmaxf(m, acc[g][r]);
    #pragma unroll
    for(int k=1;k<16;k<<=1) m = fmaxf(m, __shfl_xor(m,k,16));
    float s = 0.f;
    #pragma unroll
    for(int g=0;g<16;g++){ float e = __expf(acc[g][r]-m); acc[g][r]=e; s+=e; }
    #pragma unroll
    for(int k=1;k<16;k<<=1) s += __shfl_xor(s,k,16);
    linv[r] = 1.f/s;
  }
  #pragma unroll
  for(int g=0;g<16;g++)
    #pragma unroll
    for(int r=0;r<4;r++)
      plds[w*16 + quad*4 + r][g*16 + l15] = f2b(acc[g][r]*linv[r]);
  f32x4 acc2[4];
  #pragma unroll
  for(int i=0;i<4;i++)
    #pragma unroll
    for(int j=0;j<4;j++) acc2[i][j]=0.f;
  const u16* w2b = w2t + (long)bh*16384;
  for(int kc=0; kc<4; kc++){
    __syncthreads();
    {
      int r = t>>2, c = (t&3)*16;
      const u16* src = w2b + (long)r*256 + kc*64 + c;
      *(uint4*)&w2lds[r][c]   = *(const uint4*)src;
      *(uint4*)&w2lds[r][c+8] = *(const uint4*)(src+8);
    }
    __syncthreads();
    #pragma unroll
    for(int kk=0; kk<64; kk+=32){
      bh8 a = *(const bh8*)&plds[w*16+l15][kc*64+kk+quad*8];
      #pragma unroll
      for(int ct=0; ct<4; ct++){
        bh8 bb = *(const bh8*)&w2lds[ct*16+l15][kk+quad*8];
        acc2[ct] = __builtin_amdgcn_mfma_f32_16x16x32_bf16(a, bb, acc2[ct], 0,0,0);
      }
    }
  }
  #pragma unroll
  for(int ct=0; ct<4; ct++)
    #pragma unroll
    for(int r=0;r<4;r++){
      int nrow = n0 + w*16 + quad*4 + r;
      int d = ct*16 + l15;
      oh2[((long)b*NSEQ + nrow)*512 + h*64 + d] = f2b(acc2[ct][r]);
    }
}

// ================= depthwise conv residual: oh2 += conv(v) =================
__global__ __launch_bounds__(256) void conv_add_kernel(const u16* qkv, const u16* cw, u16* oh2){
  int bh = blockIdx.y, b = bh>>3, h = bh&7;
  int n0 = blockIdx.x*256;
  __shared__ u16 vlds[288][64];
  __shared__ float wsh[33];
  int t = threadIdx.x;
  if(t<33) wsh[t] = b2f(cw[h*33 + t]);
  for(int r = t>>2; r<288; r+=64){
    int c = (t&3)*16;
    int n = n0 - 16 + r;
    if(n>=0 && n<NSEQ){
      const u16* src = qkv + ((long)b*NSEQ + n)*1536 + 1024 + h*64 + c;
      *(uint4*)&vlds[r][c]   = *(const uint4*)src;
      *(uint4*)&vlds[r][c+8] = *(const uint4*)(src+8);
    } else {
      uint4 zz; zz.x=zz.y=zz.z=zz.w=0u;
      *(uint4*)&vlds[r][c]   = zz;
      *(uint4*)&vlds[r][c+8] = zz;
    }
  }
  __syncthreads();
  int d = t&63, sub = t>>6;
  for(int i=0;i<64;i++){
    int nloc = sub + i*4;
    float s = 0.f;
    #pragma unroll
    for(int j=0;j<33;j++) s += b2f(vlds[nloc+j][d]) * wsh[j];
    long o = ((long)b*NSEQ + n0 + nloc)*512 + h*64 + d;
    oh2[o] = f2b(b2f(oh2[o]) + s);
  }
}

// ================= host =================
extern "C" void kernel_launch(void* const* d_in, const int* in_sizes, int n_in,
                              void* d_out, int out_size, void* d_ws, size_t ws_size,
                              hipStream_t stream){
  char* wsp = (char*)d_ws;
  size_t off = 0;
  auto alloc = [&](size_t bytes)->char*{
    char* p = wsp + off; off = (off + bytes + 255) & ~(size_t)255; return p;
  };
  u16* gb   = (u16*)alloc(1024);
  u16* bb   = (u16*)alloc(1024);
  u16* bob  = (u16*)alloc(1024);
  u16* cwb  = (u16*)alloc(1024);
  u16* wqt  = (u16*)alloc(1572864);       // [1536][512]
  u16* wot  = (u16*)alloc(524288);        // [512][512]
  unsigned* flag = (unsigned*)alloc(256);
  int*  bar = (int*)alloc(256);
  float* colsum = (float*)alloc(16384);   // [16][256]
  u16*   xn   = (u16*)alloc(16777216);    // [2,8192,512]
  u16*   qkv  = (u16*)alloc(50331648);    // [16384,1536]
  u16*   ql   = (u16*)alloc(524288);
  u16*   kl   = (u16*)alloc(524288);
  u16*   ab   = (u16*)alloc(4194304);     // attn2 hilo
  u16*   zA   = (u16*)alloc(4194304);
  u16*   zB   = (u16*)alloc(4194304);
  u16*   az   = (u16*)alloc(4194304);
  u16*   t1b  = (u16*)alloc(4194304);
  u16*   t2b  = (u16*)alloc(4194304);
  u16*   kvb  = (u16*)alloc(1048576);     // kv hilo
  u16*   w2t  = (u16*)alloc(524288);      // [16,64,256]
  u16*   oh2  = (u16*)alloc(16777216);
  float* opart= (float*)alloc(8388608);   // [8][16][256][64] fp32
  float* mpart= (float*)alloc(131072);    // [8][16][256]
  float* lpart= (float*)alloc(131072);

  // 1. setup: flag, small cvt, weight transposes, zero barrier+colsum
  setup_kernel<<<dim3(1024), 256, 0, stream>>>(d_in[1], d_in[2], d_in[5], d_in[6],
                                               d_in[3], d_in[4],
                                               gb, bb, bob, cwb, wqt, wot, flag, bar, colsum);
  // 2. LayerNorm
  ln_kernel<<<dim3(16384), 256, 0, stream>>>(d_in[0], flag, gb, bb, xn);
  // 3. qkv = xn @ W_qkv
  { G128 p{}; p.A=xn; p.Bt=wqt; p.C=qkv; p.lda=512; p.ldb=512; p.ldc=1536; p.K=512;
    gemm128_kernel<<<dim3(12,128,1), 256, 0, stream>>>(p); }
  // 4. landmarks
  landmark_kernel<<<dim3(256,16), dim3(64), 0, stream>>>(qkv, ql, kl);
  // 5. sim2 + softmax + colsum
  sim2_kernel<<<dim3(4,16), 256, 0, stream>>>(ql, kl, ab, colsum);
  // 6. pinv init
  pinv_init_kernel<<<dim3(16,16), 256, 0, stream>>>(ab, colsum, zA);
  // 7. Newton-Schulz persistent (ends with z in zA)
  { NSP p{ab, zA, zB, az, t1b, t2b, bar};
    ns_kernel<<<dim3(256), 256, 0, stream>>>(p); }
  // 8. flash sim3+softmax+@v
  attn3f_kernel<<<dim3(NSPLIT,4,16), 256, 0, stream>>>(ql, qkv, opart, mpart, lpart);
  // 9. combine -> kv hilo
  kvcomb_kernel<<<dim3(1024), 256, 0, stream>>>(opart, mpart, lpart, kvb);
  // 10. W2t = (z @ kv)^T
  w2t_kernel<<<dim3(1,4,16), 256, 0, stream>>>(zA, kvb, w2t);
  // 11. fused attn1 -> oh2
  attn1_kernel<<<dim3(128,16), 256, 0, stream>>>(qkv, kl, w2t, oh2);
  // 12. conv residual
  conv_add_kernel<<<dim3(32,16), 256, 0, stream>>>(qkv, cwb, oh2);
  // 13. final: out = oh2 @ W_out + b_out + xn
  { G128 p{}; p.A=oh2; p.Bt=wot; p.C=(u16*)d_out; p.bias=bob; p.resid=xn; p.oflag=flag;
    p.lda=512; p.ldb=512; p.ldc=512; p.ldr=512; p.K=512;
    gemm128_kernel<<<dim3(4,128,1), 256, 0, stream>>>(p); }
}

// Round 6
// 631.413 us; speedup vs baseline: 2.4157x; 2.4157x over previous
//
#include <hip/hip_runtime.h>

typedef unsigned short u16;
typedef short bh8 __attribute__((ext_vector_type(8)));
typedef float f32x4 __attribute__((ext_vector_type(4)));

#define NSEQ 8192
#define ALOFF 1048576   // hi->lo element offset for 2MB-hi blocks [16][256][256]
#define KVLOFF 262144   // hi->lo element offset for kv [16][256][64]
#define NSPLIT 8        // split for flash attn3

__device__ __forceinline__ float b2f(u16 u){
  union { unsigned int u32; float f; } v; v.u32 = ((unsigned int)u) << 16; return v.f;
}
__device__ __forceinline__ u16 f2b(float f){
  union { float f; unsigned int u32; } v; v.f = f;
  unsigned int r = (v.u32 + 0x7FFFu + ((v.u32 >> 16) & 1u)) >> 16;
  return (u16)r;
}
// async global->LDS, 16B per lane; LDS dest = wave-uniform base + lane*16
__device__ __forceinline__ void glds16(const u16* g, u16* l){
  __builtin_amdgcn_global_load_lds((const __attribute__((address_space(1))) unsigned int*)g,
                                   (__attribute__((address_space(3))) unsigned int*)l, 16, 0, 0);
}

// ================= setup: flag + small cvt + weight transposes + zero colsum =================
__global__ __launch_bounds__(256) void setup_kernel(const void* g, const void* bta, const void* bo,
                                                    const void* cw, const void* wq, const void* wo,
                                                    u16* gb, u16* bb, u16* bob, u16* cwb,
                                                    u16* wqt, u16* wot,
                                                    unsigned* flag, float* colsum){
  int f32 = (((const u16*)g)[0] != 0x3F80u);
  long tid = (long)blockIdx.x*256 + threadIdx.x;
  long nth = (long)gridDim.x*256;
  if(tid==0){ *flag = (unsigned)f32; }
  for(long i=tid;i<4096;i+=nth) colsum[i]=0.f;
  for(long i=tid;i<512;i+=nth) gb[i]  = f32 ? f2b(((const float*)g)[i])   : ((const u16*)g)[i];
  for(long i=tid;i<512;i+=nth) bb[i]  = f32 ? f2b(((const float*)bta)[i]) : ((const u16*)bta)[i];
  for(long i=tid;i<512;i+=nth) bob[i] = f32 ? f2b(((const float*)bo)[i])  : ((const u16*)bo)[i];
  for(long i=tid;i<264;i+=nth) cwb[i] = f32 ? f2b(((const float*)cw)[i])  : ((const u16*)cw)[i];
  for(long i=tid;i<786432;i+=nth){
    long n = i>>9, k = i&511;
    wqt[i] = f32 ? f2b(((const float*)wq)[k*1536+n]) : ((const u16*)wq)[k*1536+n];
  }
  for(long i=tid;i<262144;i+=nth){
    long n = i>>9, k = i&511;
    wot[i] = f32 ? f2b(((const float*)wo)[k*512+n]) : ((const u16*)wo)[k*512+n];
  }
}

// ================= LayerNorm =================
__global__ __launch_bounds__(256) void ln_kernel(const void* xv, const unsigned* flag,
                                                 const u16* g, const u16* bta, u16* xn){
  int f32 = (*flag != 0u);
  long base = (long)blockIdx.x * 512;
  int t = threadIdx.x;
  float v0, v1;
  if(f32){ v0 = ((const float*)xv)[base+t]; v1 = ((const float*)xv)[base+256+t]; }
  else   { v0 = b2f(((const u16*)xv)[base+t]); v1 = b2f(((const u16*)xv)[base+256+t]); }
  float s = v0 + v1, sq = v0*v0 + v1*v1;
  #pragma unroll
  for(int k=1;k<64;k<<=1){ s += __shfl_xor(s,k,64); sq += __shfl_xor(sq,k,64); }
  __shared__ float s4[4], q4[4];
  if((t&63)==0){ s4[t>>6]=s; q4[t>>6]=sq; }
  __syncthreads();
  s = s4[0]+s4[1]+s4[2]+s4[3];
  sq = q4[0]+q4[1]+q4[2]+q4[3];
  float mu = s * (1.f/512.f);
  float var = sq * (1.f/512.f) - mu*mu;
  float inv = rsqrtf(var + 1e-5f);
  xn[base + t]       = f2b((v0-mu)*inv*b2f(g[t])     + b2f(bta[t]));
  xn[base + 256 + t] = f2b((v1-mu)*inv*b2f(g[t+256]) + b2f(bta[t+256]));
}

// ================= 128x128 MFMA GEMM with global_load_lds + XOR-swizzled LDS =================
// LDS slot (row, chunk c) holds global chunk c ^ ((row>>1)&3)  (chunk = 8 elems = 16B)
struct G128 {
  const u16 *A, *Bt; u16* C;
  const u16 *bias, *resid;
  const unsigned* oflag;
  int lda, ldb, ldc, ldr, K;
};
__global__ __launch_bounds__(256) void gemm128_kernel(G128 p){
  __shared__ u16 Ah[128][32];
  __shared__ u16 Bh[128][32];
  int t = threadIdx.x;
  int n0 = blockIdx.x*128, m0 = blockIdx.y*128;
  int w = t>>6, lane = t&63, l15 = lane&15, quad = lane>>4;
  int mw = (w>>1)*64, nw = (w&1)*64;
  int srow = lane>>2;                              // 0..15
  int schunk = ((lane&3) ^ ((srow>>1)&3))*8;       // fetch-side swizzle
  int cs = (quad ^ ((l15>>1)&3))*8;                // read-side swizzle
  f32x4 acc[4][4];
  #pragma unroll
  for(int i=0;i<4;i++)
    #pragma unroll
    for(int j=0;j<4;j++)
      #pragma unroll
      for(int k=0;k<4;k++) acc[i][j][k]=0.f;

  for(int kk=0; kk<p.K; kk+=32){
    __syncthreads();
    glds16(p.A  + (long)(m0+32*w+srow)*p.lda    + kk + schunk, &Ah[32*w][0]);
    glds16(p.A  + (long)(m0+32*w+16+srow)*p.lda + kk + schunk, &Ah[32*w+16][0]);
    glds16(p.Bt + (long)(n0+32*w+srow)*p.ldb    + kk + schunk, &Bh[32*w][0]);
    glds16(p.Bt + (long)(n0+32*w+16+srow)*p.ldb + kk + schunk, &Bh[32*w+16][0]);
    __syncthreads();
    bh8 av[4], bv[4];
    #pragma unroll
    for(int mi=0;mi<4;mi++) av[mi] = *(const bh8*)&Ah[mw + mi*16 + l15][cs];
    #pragma unroll
    for(int ni=0;ni<4;ni++) bv[ni] = *(const bh8*)&Bh[nw + ni*16 + l15][cs];
    #pragma unroll
    for(int mi=0;mi<4;mi++)
      #pragma unroll
      for(int ni=0;ni<4;ni++)
        acc[mi][ni] = __builtin_amdgcn_mfma_f32_16x16x32_bf16(av[mi], bv[ni], acc[mi][ni], 0,0,0);
  }
  int f32o = p.oflag ? (int)(*p.oflag) : 0;
  #pragma unroll
  for(int mi=0;mi<4;mi++)
    #pragma unroll
    for(int ni=0;ni<4;ni++)
      #pragma unroll
      for(int r=0;r<4;r++){
        int row = m0 + mw + mi*16 + quad*4 + r;
        int col = n0 + nw + ni*16 + l15;
        float v = acc[mi][ni][r];
        if(p.bias)  v += b2f(p.bias[col]);
        if(p.resid) v += b2f(p.resid[(long)row*p.ldr + col]);
        long coff = (long)row*p.ldc + col;
        if(p.oflag){
          if(f32o) ((float*)p.C)[coff] = v; else p.C[coff] = f2b(v);
        } else p.C[coff] = f2b(v);
      }
}

// ================= landmarks (q_l pre-scaled by 0.125) =================
__global__ __launch_bounds__(64) void landmark_kernel(const u16* qkv, u16* ql, u16* kl){
  int m = blockIdx.x, bh = blockIdx.y;
  int b = bh>>3, h = bh&7;
  int d = threadIdx.x;
  long base = ((long)b*NSEQ + (long)m*32)*1536 + h*64 + d;
  float sq=0.f, sk=0.f;
  for(int i=0;i<32;i++){
    sq += b2f(qkv[base + (long)i*1536]);
    sk += b2f(qkv[base + (long)i*1536 + 512]);
  }
  long o = ((long)bh*256 + m)*64 + d;
  ql[o] = f2b(sq * (1.f/32.f) * 0.125f);
  kl[o] = f2b(sk * (1.f/32.f));
}

// ================= fused sim2 + softmax + colsum -> attn2 hilo =================
__global__ __launch_bounds__(256) void sim2_kernel(const u16* ql, const u16* kl,
                                                   u16* ab, float* colsum){
  int mt = blockIdx.x, bh = blockIdx.y;
  __shared__ u16 qlds[64][72];
  __shared__ u16 klds[256][72];
  int t = threadIdx.x, w = t>>6, lane = t&63, l15 = lane&15, quad = lane>>4;
  {
    int r = t>>2, c = (t&3)*16;
    const u16* src = ql + (long)bh*16384 + (long)(mt*64 + r)*64 + c;
    *(uint4*)&qlds[r][c]   = *(const uint4*)src;
    *(uint4*)&qlds[r][c+8] = *(const uint4*)(src+8);
    #pragma unroll
    for(int pss=0; pss<4; pss++){
      int kr = pss*64 + r;
      const u16* ks = kl + (long)bh*16384 + (long)kr*64 + c;
      *(uint4*)&klds[kr][c]   = *(const uint4*)ks;
      *(uint4*)&klds[kr][c+8] = *(const uint4*)(ks+8);
    }
  }
  __syncthreads();
  f32x4 acc[16];
  #pragma unroll
  for(int i=0;i<16;i++)
    #pragma unroll
    for(int j=0;j<4;j++) acc[i][j]=0.f;
  #pragma unroll
  for(int g=0; g<16; g++)
    #pragma unroll
    for(int kk=0; kk<64; kk+=32){
      bh8 a  = *(const bh8*)&qlds[w*16+l15][kk+quad*8];
      bh8 bb = *(const bh8*)&klds[g*16+l15][kk+quad*8];
      acc[g] = __builtin_amdgcn_mfma_f32_16x16x32_bf16(a, bb, acc[g], 0,0,0);
    }
  #pragma unroll
  for(int r=0;r<4;r++){
    float m = -3.0e38f;
    #pragma unroll
    for(int g=0;g<16;g++) m = fmaxf(m, acc[g][r]);
    #pragma unroll
    for(int k=1;k<16;k<<=1) m = fmaxf(m, __shfl_xor(m,k,16));
    float s = 0.f;
    #pragma unroll
    for(int g=0;g<16;g++){ float e = __expf(acc[g][r]-m); acc[g][r]=e; s+=e; }
    #pragma unroll
    for(int k=1;k<16;k<<=1) s += __shfl_xor(s,k,16);
    float inv = 1.f/s;
    #pragma unroll
    for(int g=0;g<16;g++) acc[g][r] *= inv;
  }
  long bbase = (long)bh*65536;
  #pragma unroll
  for(int g=0;g<16;g++){
    float ps = 0.f;
    #pragma unroll
    for(int r=0;r<4;r++){
      int row = mt*64 + w*16 + quad*4 + r;
      int col = g*16 + l15;
      float pv = acc[g][r];
      u16 h = f2b(pv);
      ab[bbase + (long)row*256 + col] = h;
      ab[ALOFF + bbase + (long)row*256 + col] = f2b(pv - b2f(h));
      ps += pv;
    }
    ps += __shfl_xor(ps, 16);
    ps += __shfl_xor(ps, 32);
    if(quad==0) atomicAdd(&colsum[bh*256 + g*16 + l15], ps);
  }
}

// ================= pinv init: z0 = a^T / colmax  (hilo out) =================
__global__ __launch_bounds__(256) void pinv_init_kernel(const u16* ah, const float* colsum, u16* zh){
  int tile = blockIdx.x, bh = blockIdx.y;
  int tx = tile&3, ty = tile>>2;
  __shared__ u16 th[64][72], tl[64][72];
  __shared__ float red[4];
  int t = threadIdx.x;
  float mc = 0.f;
  for(int i=t;i<4096;i+=256) mc = fmaxf(mc, colsum[i]);
  #pragma unroll
  for(int k=1;k<64;k<<=1) mc = fmaxf(mc, __shfl_xor(mc,k,64));
  if((t&63)==0) red[t>>6]=mc;
  int r = t>>2, c = (t&3)*16;
  const u16* src = ah + (long)bh*65536 + (long)(ty*64 + r)*256 + tx*64 + c;
  *(uint4*)&th[r][c]   = *(const uint4*)src;
  *(uint4*)&th[r][c+8] = *(const uint4*)(src+8);
  *(uint4*)&tl[r][c]   = *(const uint4*)(src+ALOFF);
  *(uint4*)&tl[r][c+8] = *(const uint4*)(src+ALOFF+8);
  __syncthreads();
  float dinv = 1.f/fmaxf(fmaxf(red[0],red[1]), fmaxf(red[2],red[3]));
  u16 oh[16], ol[16];
  #pragma unroll
  for(int jj=0;jj<16;jj++){
    float v = (b2f(th[c+jj][r]) + b2f(tl[c+jj][r])) * dinv;
    u16 h = f2b(v);
    oh[jj] = h; ol[jj] = f2b(v - b2f(h));
  }
  u16* dst = zh + (long)bh*65536 + (long)(tx*64 + r)*256 + ty*64 + c;
  *(uint4*)dst     = *(uint4*)oh;
  *(uint4*)(dst+8) = *(uint4*)(oh+8);
  *(uint4*)(dst+ALOFF)   = *(uint4*)ol;
  *(uint4*)(dst+ALOFF+8) = *(uint4*)(ol+8);
}

// ================= Newton-Schulz hilo GEMM (one of 24 launches) =================
// C = alpha*(A@B) + beta*I  [dual: C2 = alpha2*AB + beta2*I], all hilo bf16.
struct NSG { const u16 *A, *B; u16 *Ch, *Cl, *C2h, *C2l; float alpha, beta, alpha2, beta2; };
__global__ __launch_bounds__(256) void ns_gemm_kernel(NSG p){
  __shared__ u16 Ah[64][40], Al[64][40], Bh[64][40], Bl[64][40];
  int t = threadIdx.x;
  long boff = (long)blockIdx.z*65536;
  int n0 = blockIdx.x*64, m0 = blockIdx.y*64;
  int w = t>>6, lane = t&63, l15 = lane&15, quad = lane>>4;
  int ar = t>>2, ac = (t&3)*8;
  int bk = t>>3, bn = (t&7)*8;
  f32x4 acc[4];
  #pragma unroll
  for(int i=0;i<4;i++)
    #pragma unroll
    for(int j=0;j<4;j++) acc[i][j]=0.f;
  for(int kk=0; kk<256; kk+=32){
    __syncthreads();
    *(uint4*)&Ah[ar][ac] = *(const uint4*)(p.A + boff + (long)(m0+ar)*256 + kk + ac);
    *(uint4*)&Al[ar][ac] = *(const uint4*)(p.A + ALOFF + boff + (long)(m0+ar)*256 + kk + ac);
    u16 th[8], tl[8];
    *(uint4*)th = *(const uint4*)(p.B + boff + (long)(kk+bk)*256 + n0 + bn);
    *(uint4*)tl = *(const uint4*)(p.B + ALOFF + boff + (long)(kk+bk)*256 + n0 + bn);
    #pragma unroll
    for(int j=0;j<8;j++){ Bh[bn+j][bk] = th[j]; Bl[bn+j][bk] = tl[j]; }
    __syncthreads();
    bh8 a  = *(const bh8*)&Ah[w*16+l15][quad*8];
    bh8 al = *(const bh8*)&Al[w*16+l15][quad*8];
    #pragma unroll
    for(int ct=0; ct<4; ct++){
      bh8 b  = *(const bh8*)&Bh[ct*16+l15][quad*8];
      bh8 bl = *(const bh8*)&Bl[ct*16+l15][quad*8];
      acc[ct] = __builtin_amdgcn_mfma_f32_16x16x32_bf16(a,  b,  acc[ct], 0,0,0);
      acc[ct] = __builtin_amdgcn_mfma_f32_16x16x32_bf16(a,  bl, acc[ct], 0,0,0);
      acc[ct] = __builtin_amdgcn_mfma_f32_16x16x32_bf16(al, b,  acc[ct], 0,0,0);
    }
  }
  #pragma unroll
  for(int ct=0; ct<4; ct++)
    #pragma unroll
    for(int r=0;r<4;r++){
      int col = n0 + ct*16 + l15;
      int row = m0 + w*16 + quad*4 + r;
      long coff = boff + (long)row*256 + col;
      float v = acc[ct][r];
      float v1 = p.alpha*v + ((row==col) ? p.beta : 0.f);
      u16 h = f2b(v1);
      p.Ch[coff] = h;
      p.Cl[coff] = f2b(v1 - b2f(h));
      if(p.C2h){
        float v2 = p.alpha2*v + ((row==col) ? p.beta2 : 0.f);
        u16 h2 = f2b(v2);
        p.C2h[coff] = h2;
        p.C2l[coff] = f2b(v2 - b2f(h2));
      }
    }
}

// ================= W2t = (z @ kv)^T  (hilo in, bf16 out transposed) =================
__global__ __launch_bounds__(256) void w2t_kernel(const u16* z, const u16* kvh, u16* w2t){
  __shared__ u16 Ah[64][40], Al[64][40], Bh[64][40], Bl[64][40];
  int t = threadIdx.x;
  int bh = blockIdx.z;
  int m0 = blockIdx.y*64;
  long za = (long)bh*65536;
  long kb = (long)bh*16384;
  int w = t>>6, lane = t&63, l15 = lane&15, quad = lane>>4;
  int ar = t>>2, ac = (t&3)*8;
  int bk = t>>3, bn = (t&7)*8;
  f32x4 acc[4];
  #pragma unroll
  for(int i=0;i<4;i++)
    #pragma unroll
    for(int j=0;j<4;j++) acc[i][j]=0.f;
  for(int kk=0; kk<256; kk+=32){
    __syncthreads();
    *(uint4*)&Ah[ar][ac] = *(const uint4*)(z + za + (long)(m0+ar)*256 + kk + ac);
    *(uint4*)&Al[ar][ac] = *(const uint4*)(z + ALOFF + za + (long)(m0+ar)*256 + kk + ac);
    u16 th[8], tl[8];
    *(uint4*)th = *(const uint4*)(kvh + kb + (long)(kk+bk)*64 + bn);
    *(uint4*)tl = *(const uint4*)(kvh + KVLOFF + kb + (long)(kk+bk)*64 + bn);
    #pragma unroll
    for(int j=0;j<8;j++){ Bh[bn+j][bk] = th[j]; Bl[bn+j][bk] = tl[j]; }
    __syncthreads();
    bh8 a  = *(const bh8*)&Ah[w*16+l15][quad*8];
    bh8 al = *(const bh8*)&Al[w*16+l15][quad*8];
    #pragma unroll
    for(int ct=0; ct<4; ct++){
      bh8 b  = *(const bh8*)&Bh[ct*16+l15][quad*8];
      bh8 bl = *(const bh8*)&Bl[ct*16+l15][quad*8];
      acc[ct] = __builtin_amdgcn_mfma_f32_16x16x32_bf16(a,  b,  acc[ct], 0,0,0);
      acc[ct] = __builtin_amdgcn_mfma_f32_16x16x32_bf16(a,  bl, acc[ct], 0,0,0);
      acc[ct] = __builtin_amdgcn_mfma_f32_16x16x32_bf16(al, b,  acc[ct], 0,0,0);
    }
  }
  #pragma unroll
  for(int ct=0; ct<4; ct++)
    #pragma unroll
    for(int r=0;r<4;r++){
      int col = ct*16 + l15;
      int row = m0 + w*16 + quad*4 + r;
      w2t[kb + (long)col*256 + row] = f2b(acc[ct][r]);
    }
}

// ================= flash sim3+softmax+@v (split over seq) =================
__global__ __launch_bounds__(256) void attn3f_kernel(const u16* ql, const u16* qkv,
                                                     float* opart, float* mpart, float* lpart){
  int s = blockIdx.x, mt = blockIdx.y, bh = blockIdx.z;
  int b = bh>>3, h = bh&7;
  __shared__ u16 qlds[64][72];
  __shared__ u16 Kh[128][72];
  __shared__ u16 Vt[64][136];
  __shared__ u16 plds[64][136];
  int t = threadIdx.x, w = t>>6, lane = t&63, l15 = lane&15, quad = lane>>4;
  {
    int r = t>>2, c = (t&3)*16;
    const u16* src = ql + (long)bh*16384 + (long)(mt*64 + r)*64 + c;
    *(uint4*)&qlds[r][c]   = *(const uint4*)src;
    *(uint4*)&qlds[r][c+8] = *(const uint4*)(src+8);
  }
  float mrun[4], lrun[4];
  #pragma unroll
  for(int r=0;r<4;r++){ mrun[r] = -3.0e38f; lrun[r] = 0.f; }
  f32x4 O[4];
  #pragma unroll
  for(int i=0;i<4;i++)
    #pragma unroll
    for(int j=0;j<4;j++) O[i][j]=0.f;

  for(int ch=0; ch<8; ch++){
    long n0 = (long)s*1024 + ch*128;
    __syncthreads();
    #pragma unroll
    for(int pss=0; pss<4; pss++){
      int r = pss*32 + (t>>3), c = (t&7)*8;
      const u16* ksrc = qkv + 512 + ((long)b*NSEQ + n0 + r)*1536 + h*64 + c;
      *(uint4*)&Kh[r][c] = *(const uint4*)ksrc;
      u16 tv[8];
      *(uint4*)tv = *(const uint4*)(ksrc + 512);
      #pragma unroll
      for(int j=0;j<8;j++) Vt[c+j][r] = tv[j];
    }
    __syncthreads();
    f32x4 sc[8];
    #pragma unroll
    for(int i=0;i<8;i++)
      #pragma unroll
      for(int j=0;j<4;j++) sc[i][j]=0.f;
    #pragma unroll
    for(int g=0; g<8; g++)
      #pragma unroll
      for(int kk=0; kk<64; kk+=32){
        bh8 a  = *(const bh8*)&qlds[w*16+l15][kk+quad*8];
        bh8 bb = *(const bh8*)&Kh[g*16+l15][kk+quad*8];
        sc[g] = __builtin_amdgcn_mfma_f32_16x16x32_bf16(a, bb, sc[g], 0,0,0);
      }
    #pragma unroll
    for(int r=0;r<4;r++){
      float cm = -3.0e38f;
      #pragma unroll
      for(int g=0;g<8;g++) cm = fmaxf(cm, sc[g][r]);
      #pragma unroll
      for(int k=1;k<16;k<<=1) cm = fmaxf(cm, __shfl_xor(cm,k,16));
      float nm = fmaxf(mrun[r], cm);
      float alpha = __expf(mrun[r]-nm);
      mrun[r] = nm;
      float psum = 0.f;
      #pragma unroll
      for(int g=0;g<8;g++){ float e = __expf(sc[g][r]-nm); sc[g][r]=e; psum+=e; }
      #pragma unroll
      for(int k=1;k<16;k<<=1) psum += __shfl_xor(psum,k,16);
      lrun[r] = lrun[r]*alpha + psum;
      #pragma unroll
      for(int ct=0;ct<4;ct++) O[ct][r] *= alpha;
    }
    #pragma unroll
    for(int g=0;g<8;g++)
      #pragma unroll
      for(int r=0;r<4;r++)
        plds[w*16 + quad*4 + r][g*16 + l15] = f2b(sc[g][r]);
    __syncthreads();
    #pragma unroll
    for(int kk=0; kk<128; kk+=32){
      bh8 a = *(const bh8*)&plds[w*16+l15][kk+quad*8];
      #pragma unroll
      for(int ct=0; ct<4; ct++){
        bh8 bb = *(const bh8*)&Vt[ct*16+l15][kk+quad*8];
        O[ct] = __builtin_amdgcn_mfma_f32_16x16x32_bf16(a, bb, O[ct], 0,0,0);
      }
    }
  }
  long rbase = (long)(s*16 + bh)*256 + mt*64 + w*16;
  #pragma unroll
  for(int ct=0; ct<4; ct++)
    #pragma unroll
    for(int r=0;r<4;r++)
      opart[(rbase + quad*4 + r)*64 + ct*16 + l15] = O[ct][r];
  if(l15==0){
    #pragma unroll
    for(int r=0;r<4;r++){
      mpart[rbase + quad*4 + r] = mrun[r];
      lpart[rbase + quad*4 + r] = lrun[r];
    }
  }
}

// ================= combine flash partials -> kv hilo =================
__global__ __launch_bounds__(256) void kvcomb_kernel(const float* opart, const float* mpart,
                                                     const float* lpart, u16* kvh){
  long i = (long)blockIdx.x*256 + threadIdx.x;
  int col = (int)(i & 63);
  long rb = i >> 6;
  float M = -3.0e38f;
  #pragma unroll
  for(int s=0;s<NSPLIT;s++) M = fmaxf(M, mpart[(long)s*4096 + rb]);
  float num = 0.f, den = 0.f;
  #pragma unroll
  for(int s=0;s<NSPLIT;s++){
    float e = __expf(mpart[(long)s*4096 + rb] - M);
    den += e * lpart[(long)s*4096 + rb];
    num += e * opart[((long)s*4096 + rb)*64 + col];
  }
  float v = num/den;
  u16 h = f2b(v);
  kvh[i] = h;
  kvh[KVLOFF + i] = f2b(v - b2f(h));
}

// ================= fused attn1 path: oh2 = softmax(0.125*q@kl^T) @ W2 =================
__global__ __launch_bounds__(256) void attn1_kernel(const u16* qkv, const u16* kl,
                                                    const u16* w2t, u16* oh2){
  int bh = blockIdx.y, b = bh>>3, h = bh&7;
  int n0 = blockIdx.x*64;
  __shared__ u16 qlds[64][72];
  __shared__ u16 klds[64][72];
  __shared__ u16 plds[64][264];
  __shared__ u16 w2lds[64][72];
  int t = threadIdx.x, w = t>>6, lane = t&63, l15 = lane&15, quad = lane>>4;
  {
    int r = t>>2, c = (t&3)*16;
    const u16* src = qkv + ((long)b*NSEQ + n0 + r)*1536 + h*64 + c;
    *(uint4*)&qlds[r][c]   = *(const uint4*)src;
    *(uint4*)&qlds[r][c+8] = *(const uint4*)(src+8);
  }
  f32x4 acc[16];
  #pragma unroll
  for(int i=0;i<16;i++)
    #pragma unroll
    for(int j=0;j<4;j++) acc[i][j]=0.f;
  const u16* klb = kl + (long)bh*16384;
  for(int nt=0; nt<4; nt++){
    __syncthreads();
    {
      int r = t>>2, c = (t&3)*16;
      const u16* src = klb + (long)(nt*64 + r)*64 + c;
      *(uint4*)&klds[r][c]   = *(const uint4*)src;
      *(uint4*)&klds[r][c+8] = *(const uint4*)(src+8);
    }
    __syncthreads();
    #pragma unroll
    for(int kk=0; kk<64; kk+=32){
      bh8 a = *(const bh8*)&qlds[w*16+l15][kk+quad*8];
      #pragma unroll
      for(int ct=0; ct<4; ct++){
        bh8 bb = *(const bh8*)&klds[ct*16+l15][kk+quad*8];
        acc[nt*4+ct] = __builtin_amdgcn_mfma_f32_16x16x32_bf16(a, bb, acc[nt*4+ct], 0,0,0);
      }
    }
  }
  float linv[4];
  #pragma unroll
  for(int g=0; g<16; g++)
    #pragma unroll
    for(int r=0;r<4;r++) acc[g][r] *= 0.125f;
  #pragma unroll
  for(int r=0;r<4;r++){
    float m = -3.0e38f;
    #pragma unroll
    for(int g=0;g<16;g++) m = fmaxf(m, acc[g][r]);
    #pragma unroll
    for(int k=1;k<16;k<<=1) m = fmaxf(m, __shfl_xor(m,k,16));
    float s = 0.f;
    #pragma unroll
    for(int g=0;g<16;g++){ float e = __expf(acc[g][r]-m); acc[g][r]=e; s+=e; }
    #pragma unroll
    for(int k=1;k<16;k<<=1) s += __shfl_xor(s,k,16);
    linv[r] = 1.f/s;
  }
  #pragma unroll
  for(int g=0;g<16;g++)
    #pragma unroll
    for(int r=0;r<4;r++)
      plds[w*16 + quad*4 + r][g*16 + l15] = f2b(acc[g][r]*linv[r]);
  f32x4 acc2[4];
  #pragma unroll
  for(int i=0;i<4;i++)
    #pragma unroll
    for(int j=0;j<4;j++) acc2[i][j]=0.f;
  const u16* w2b = w2t + (long)bh*16384;
  for(int kc=0; kc<4; kc++){
    __syncthreads();
    {
      int r = t>>2, c = (t&3)*16;
      const u16* src = w2b + (long)r*256 + kc*64 + c;
      *(uint4*)&w2lds[r][c]   = *(const uint4*)src;
      *(uint4*)&w2lds[r][c+8] = *(const uint4*)(src+8);
    }
    __syncthreads();
    #pragma unroll
    for(int kk=0; kk<64; kk+=32){
      bh8 a = *(const bh8*)&plds[w*16+l15][kc*64+kk+quad*8];
      #pragma unroll
      for(int ct=0; ct<4; ct++){
        bh8 bb = *(const bh8*)&w2lds[ct*16+l15][kk+quad*8];
        acc2[ct] = __builtin_amdgcn_mfma_f32_16x16x32_bf16(a, bb, acc2[ct], 0,0,0);
      }
    }
  }
  #pragma unroll
  for(int ct=0; ct<4; ct++)
    #pragma unroll
    for(int r=0;r<4;r++){
      int nrow = n0 + w*16 + quad*4 + r;
      int d = ct*16 + l15;
      oh2[((long)b*NSEQ + nrow)*512 + h*64 + d] = f2b(acc2[ct][r]);
    }
}

// ================= depthwise conv residual: oh2 += conv(v) =================
__global__ __launch_bounds__(256) void conv_add_kernel(const u16* qkv, const u16* cw, u16* oh2){
  int bh = blockIdx.y, b = bh>>3, h = bh&7;
  int n0 = blockIdx.x*256;
  __shared__ u16 vlds[288][64];
  __shared__ float wsh[33];
  int t = threadIdx.x;
  if(t<33) wsh[t] = b2f(cw[h*33 + t]);
  for(int r = t>>2; r<288; r+=64){
    int c = (t&3)*16;
    int n = n0 - 16 + r;
    if(n>=0 && n<NSEQ){
      const u16* src = qkv + ((long)b*NSEQ + n)*1536 + 1024 + h*64 + c;
      *(uint4*)&vlds[r][c]   = *(const uint4*)src;
      *(uint4*)&vlds[r][c+8] = *(const uint4*)(src+8);
    } else {
      uint4 zz; zz.x=zz.y=zz.z=zz.w=0u;
      *(uint4*)&vlds[r][c]   = zz;
      *(uint4*)&vlds[r][c+8] = zz;
    }
  }
  __syncthreads();
  int d = t&63, sub = t>>6;
  for(int i=0;i<64;i++){
    int nloc = sub + i*4;
    float s = 0.f;
    #pragma unroll
    for(int j=0;j<33;j++) s += b2f(vlds[nloc+j][d]) * wsh[j];
    long o = ((long)b*NSEQ + n0 + nloc)*512 + h*64 + d;
    oh2[o] = f2b(b2f(oh2[o]) + s);
  }
}

// ================= host =================
extern "C" void kernel_launch(void* const* d_in, const int* in_sizes, int n_in,
                              void* d_out, int out_size, void* d_ws, size_t ws_size,
                              hipStream_t stream){
  char* wsp = (char*)d_ws;
  size_t off = 0;
  auto alloc = [&](size_t bytes)->char*{
    char* p = wsp + off; off = (off + bytes + 255) & ~(size_t)255; return p;
  };
  u16* gb   = (u16*)alloc(1024);
  u16* bb   = (u16*)alloc(1024);
  u16* bob  = (u16*)alloc(1024);
  u16* cwb  = (u16*)alloc(1024);
  u16* wqt  = (u16*)alloc(1572864);       // [1536][512]
  u16* wot  = (u16*)alloc(524288);        // [512][512]
  unsigned* flag = (unsigned*)alloc(256);
  float* colsum = (float*)alloc(16384);   // [16][256]
  u16*   xn   = (u16*)alloc(16777216);    // [2,8192,512]
  u16*   qkv  = (u16*)alloc(50331648);    // [16384,1536]
  u16*   ql   = (u16*)alloc(524288);
  u16*   kl   = (u16*)alloc(524288);
  u16*   ab   = (u16*)alloc(4194304);     // attn2 hilo
  u16*   zA   = (u16*)alloc(4194304);
  u16*   zB   = (u16*)alloc(4194304);
  u16*   az   = (u16*)alloc(4194304);
  u16*   t1b  = (u16*)alloc(4194304);
  u16*   t2b  = (u16*)alloc(4194304);
  u16*   kvb  = (u16*)alloc(1048576);     // kv hilo
  u16*   w2t  = (u16*)alloc(524288);      // [16,64,256]
  u16*   oh2  = (u16*)alloc(16777216);
  float* opart= (float*)alloc(8388608);   // [8][16][256][64] fp32
  float* mpart= (float*)alloc(131072);
  float* lpart= (float*)alloc(131072);

  // 1. setup
  setup_kernel<<<dim3(1024), 256, 0, stream>>>(d_in[1], d_in[2], d_in[5], d_in[6],
                                               d_in[3], d_in[4],
                                               gb, bb, bob, cwb, wqt, wot, flag, colsum);
  // 2. LayerNorm
  ln_kernel<<<dim3(16384), 256, 0, stream>>>(d_in[0], flag, gb, bb, xn);
  // 3. qkv = xn @ W_qkv
  { G128 p{}; p.A=xn; p.Bt=wqt; p.C=qkv; p.lda=512; p.ldb=512; p.ldc=1536; p.K=512;
    gemm128_kernel<<<dim3(12,128,1), 256, 0, stream>>>(p); }
  // 4. landmarks
  landmark_kernel<<<dim3(256,16), dim3(64), 0, stream>>>(qkv, ql, kl);
  // 5. sim2 + softmax + colsum
  sim2_kernel<<<dim3(4,16), 256, 0, stream>>>(ql, kl, ab, colsum);
  // 6. pinv init
  pinv_init_kernel<<<dim3(16,16), 256, 0, stream>>>(ab, colsum, zA);
  // 7. Newton-Schulz: 24 small hilo GEMM launches (proven path)
  { u16* zc = zA; u16* zn = zB;
    for(int it=0; it<6; it++){
      { NSG q{ab, zc, az, az+ALOFF, t1b, t1b+ALOFF, 1.f, 0.f, -1.f, 7.f};
        ns_gemm_kernel<<<dim3(4,4,16), 256, 0, stream>>>(q); }
      { NSG q{az, t1b, t2b, t2b+ALOFF, nullptr, nullptr, -1.f, 15.f, 0.f, 0.f};
        ns_gemm_kernel<<<dim3(4,4,16), 256, 0, stream>>>(q); }
      { NSG q{az, t2b, t1b, t1b+ALOFF, nullptr, nullptr, -1.f, 13.f, 0.f, 0.f};
        ns_gemm_kernel<<<dim3(4,4,16), 256, 0, stream>>>(q); }
      { NSG q{zc, t1b, zn, zn+ALOFF, nullptr, nullptr, 0.25f, 0.f, 0.f, 0.f};
        ns_gemm_kernel<<<dim3(4,4,16), 256, 0, stream>>>(q); }
      u16* tmp = zc; zc = zn; zn = tmp;
    } }
  // 8. flash sim3+softmax+@v
  attn3f_kernel<<<dim3(NSPLIT,4,16), 256, 0, stream>>>(ql, qkv, opart, mpart, lpart);
  // 9. combine -> kv hilo
  kvcomb_kernel<<<dim3(1024), 256, 0, stream>>>(opart, mpart, lpart, kvb);
  // 10. W2t = (z @ kv)^T   (z ends in zA after 6 iterations)
  w2t_kernel<<<dim3(1,4,16), 256, 0, stream>>>(zA, kvb, w2t);
  // 11. fused attn1 -> oh2
  attn1_kernel<<<dim3(128,16), 256, 0, stream>>>(qkv, kl, w2t, oh2);
  // 12. conv residual
  conv_add_kernel<<<dim3(32,16), 256, 0, stream>>>(qkv, cwb, oh2);
  // 13. final: out = oh2 @ W_out + b_out + xn
  { G128 p{}; p.A=oh2; p.Bt=wot; p.C=(u16*)d_out; p.bias=bob; p.resid=xn; p.oflag=flag;
    p.lda=512; p.ldb=512; p.ldc=512; p.ldr=512; p.K=512;
    gemm128_kernel<<<dim3(4,128,1), 256, 0, stream>>>(p); }
}

// Round 7
// 587.974 us; speedup vs baseline: 2.5942x; 1.0739x over previous
//
#include <hip/hip_runtime.h>

typedef unsigned short u16;
typedef short bh8 __attribute__((ext_vector_type(8)));
typedef float f32x4 __attribute__((ext_vector_type(4)));

#define NSEQ 8192
#define ALOFF 1048576   // hi->lo element offset for 2MB-hi blocks [16][256][256]
#define KVLOFF 262144   // hi->lo element offset for kv [16][256][64]
#define NSPLIT 8        // split for flash attn3

__device__ __forceinline__ float b2f(u16 u){
  union { unsigned int u32; float f; } v; v.u32 = ((unsigned int)u) << 16; return v.f;
}
__device__ __forceinline__ u16 f2b(float f){
  union { float f; unsigned int u32; } v; v.f = f;
  unsigned int r = (v.u32 + 0x7FFFu + ((v.u32 >> 16) & 1u)) >> 16;
  return (u16)r;
}
__device__ __forceinline__ void glds16(const u16* g, u16* l){
  __builtin_amdgcn_global_load_lds((const __attribute__((address_space(1))) unsigned int*)g,
                                   (__attribute__((address_space(3))) unsigned int*)l, 16, 0, 0);
}

// ================= setup =================
__global__ __launch_bounds__(256) void setup_kernel(const void* g, const void* bta, const void* bo,
                                                    const void* cw, const void* wq, const void* wo,
                                                    u16* gb, u16* bb, u16* bob, u16* cwb,
                                                    u16* wqt, u16* wot,
                                                    unsigned* flag, float* colsum){
  int f32 = (((const u16*)g)[0] != 0x3F80u);
  long tid = (long)blockIdx.x*256 + threadIdx.x;
  long nth = (long)gridDim.x*256;
  if(tid==0){ *flag = (unsigned)f32; }
  for(long i=tid;i<4096;i+=nth) colsum[i]=0.f;
  for(long i=tid;i<512;i+=nth) gb[i]  = f32 ? f2b(((const float*)g)[i])   : ((const u16*)g)[i];
  for(long i=tid;i<512;i+=nth) bb[i]  = f32 ? f2b(((const float*)bta)[i]) : ((const u16*)bta)[i];
  for(long i=tid;i<512;i+=nth) bob[i] = f32 ? f2b(((const float*)bo)[i])  : ((const u16*)bo)[i];
  for(long i=tid;i<264;i+=nth) cwb[i] = f32 ? f2b(((const float*)cw)[i])  : ((const u16*)cw)[i];
  for(long i=tid;i<786432;i+=nth){
    long n = i>>9, k = i&511;
    wqt[i] = f32 ? f2b(((const float*)wq)[k*1536+n]) : ((const u16*)wq)[k*1536+n];
  }
  for(long i=tid;i<262144;i+=nth){
    long n = i>>9, k = i&511;
    wot[i] = f32 ? f2b(((const float*)wo)[k*512+n]) : ((const u16*)wo)[k*512+n];
  }
}

// ================= LayerNorm =================
__global__ __launch_bounds__(256) void ln_kernel(const void* xv, const unsigned* flag,
                                                 const u16* g, const u16* bta, u16* xn){
  int f32 = (*flag != 0u);
  long base = (long)blockIdx.x * 512;
  int t = threadIdx.x;
  float v0, v1;
  if(f32){ v0 = ((const float*)xv)[base+t]; v1 = ((const float*)xv)[base+256+t]; }
  else   { v0 = b2f(((const u16*)xv)[base+t]); v1 = b2f(((const u16*)xv)[base+256+t]); }
  float s = v0 + v1, sq = v0*v0 + v1*v1;
  #pragma unroll
  for(int k=1;k<64;k<<=1){ s += __shfl_xor(s,k,64); sq += __shfl_xor(sq,k,64); }
  __shared__ float s4[4], q4[4];
  if((t&63)==0){ s4[t>>6]=s; q4[t>>6]=sq; }
  __syncthreads();
  s = s4[0]+s4[1]+s4[2]+s4[3];
  sq = q4[0]+q4[1]+q4[2]+q4[3];
  float mu = s * (1.f/512.f);
  float var = sq * (1.f/512.f) - mu*mu;
  float inv = rsqrtf(var + 1e-5f);
  xn[base + t]       = f2b((v0-mu)*inv*b2f(g[t])     + b2f(bta[t]));
  xn[base + 256 + t] = f2b((v1-mu)*inv*b2f(g[t+256]) + b2f(bta[t+256]));
}

// ================= 128x128 MFMA GEMM (glds16 + XOR swizzle) =================
struct G128 {
  const u16 *A, *Bt; u16* C;
  const u16 *bias, *resid;
  const unsigned* oflag;
  int lda, ldb, ldc, ldr, K;
};
__global__ __launch_bounds__(256) void gemm128_kernel(G128 p){
  __shared__ u16 Ah[128][32];
  __shared__ u16 Bh[128][32];
  int t = threadIdx.x;
  int n0 = blockIdx.x*128, m0 = blockIdx.y*128;
  int w = t>>6, lane = t&63, l15 = lane&15, quad = lane>>4;
  int mw = (w>>1)*64, nw = (w&1)*64;
  int srow = lane>>2;
  int schunk = ((lane&3) ^ ((srow>>1)&3))*8;
  int cs = (quad ^ ((l15>>1)&3))*8;
  f32x4 acc[4][4];
  #pragma unroll
  for(int i=0;i<4;i++)
    #pragma unroll
    for(int j=0;j<4;j++)
      #pragma unroll
      for(int k=0;k<4;k++) acc[i][j][k]=0.f;

  for(int kk=0; kk<p.K; kk+=32){
    __syncthreads();
    glds16(p.A  + (long)(m0+32*w+srow)*p.lda    + kk + schunk, &Ah[32*w][0]);
    glds16(p.A  + (long)(m0+32*w+16+srow)*p.lda + kk + schunk, &Ah[32*w+16][0]);
    glds16(p.Bt + (long)(n0+32*w+srow)*p.ldb    + kk + schunk, &Bh[32*w][0]);
    glds16(p.Bt + (long)(n0+32*w+16+srow)*p.ldb + kk + schunk, &Bh[32*w+16][0]);
    __syncthreads();
    bh8 av[4], bv[4];
    #pragma unroll
    for(int mi=0;mi<4;mi++) av[mi] = *(const bh8*)&Ah[mw + mi*16 + l15][cs];
    #pragma unroll
    for(int ni=0;ni<4;ni++) bv[ni] = *(const bh8*)&Bh[nw + ni*16 + l15][cs];
    #pragma unroll
    for(int mi=0;mi<4;mi++)
      #pragma unroll
      for(int ni=0;ni<4;ni++)
        acc[mi][ni] = __builtin_amdgcn_mfma_f32_16x16x32_bf16(av[mi], bv[ni], acc[mi][ni], 0,0,0);
  }
  int f32o = p.oflag ? (int)(*p.oflag) : 0;
  #pragma unroll
  for(int mi=0;mi<4;mi++)
    #pragma unroll
    for(int ni=0;ni<4;ni++)
      #pragma unroll
      for(int r=0;r<4;r++){
        int row = m0 + mw + mi*16 + quad*4 + r;
        int col = n0 + nw + ni*16 + l15;
        float v = acc[mi][ni][r];
        if(p.bias)  v += b2f(p.bias[col]);
        if(p.resid) v += b2f(p.resid[(long)row*p.ldr + col]);
        long coff = (long)row*p.ldc + col;
        if(p.oflag){
          if(f32o) ((float*)p.C)[coff] = v; else p.C[coff] = f2b(v);
        } else p.C[coff] = f2b(v);
      }
}

// ================= landmarks =================
__global__ __launch_bounds__(64) void landmark_kernel(const u16* qkv, u16* ql, u16* kl){
  int m = blockIdx.x, bh = blockIdx.y;
  int b = bh>>3, h = bh&7;
  int d = threadIdx.x;
  long base = ((long)b*NSEQ + (long)m*32)*1536 + h*64 + d;
  float sq=0.f, sk=0.f;
  for(int i=0;i<32;i++){
    sq += b2f(qkv[base + (long)i*1536]);
    sk += b2f(qkv[base + (long)i*1536 + 512]);
  }
  long o = ((long)bh*256 + m)*64 + d;
  ql[o] = f2b(sq * (1.f/32.f) * 0.125f);
  kl[o] = f2b(sk * (1.f/32.f));
}

// ================= fused sim2 + softmax + colsum =================
__global__ __launch_bounds__(256) void sim2_kernel(const u16* ql, const u16* kl,
                                                   u16* ab, float* colsum){
  int mt = blockIdx.x, bh = blockIdx.y;
  __shared__ u16 qlds[64][72];
  __shared__ u16 klds[256][72];
  int t = threadIdx.x, w = t>>6, lane = t&63, l15 = lane&15, quad = lane>>4;
  {
    int r = t>>2, c = (t&3)*16;
    const u16* src = ql + (long)bh*16384 + (long)(mt*64 + r)*64 + c;
    *(uint4*)&qlds[r][c]   = *(const uint4*)src;
    *(uint4*)&qlds[r][c+8] = *(const uint4*)(src+8);
    #pragma unroll
    for(int pss=0; pss<4; pss++){
      int kr = pss*64 + r;
      const u16* ks = kl + (long)bh*16384 + (long)kr*64 + c;
      *(uint4*)&klds[kr][c]   = *(const uint4*)ks;
      *(uint4*)&klds[kr][c+8] = *(const uint4*)(ks+8);
    }
  }
  __syncthreads();
  f32x4 acc[16];
  #pragma unroll
  for(int i=0;i<16;i++)
    #pragma unroll
    for(int j=0;j<4;j++) acc[i][j]=0.f;
  #pragma unroll
  for(int g=0; g<16; g++)
    #pragma unroll
    for(int kk=0; kk<64; kk+=32){
      bh8 a  = *(const bh8*)&qlds[w*16+l15][kk+quad*8];
      bh8 bb = *(const bh8*)&klds[g*16+l15][kk+quad*8];
      acc[g] = __builtin_amdgcn_mfma_f32_16x16x32_bf16(a, bb, acc[g], 0,0,0);
    }
  #pragma unroll
  for(int r=0;r<4;r++){
    float m = -3.0e38f;
    #pragma unroll
    for(int g=0;g<16;g++) m = fmaxf(m, acc[g][r]);
    #pragma unroll
    for(int k=1;k<16;k<<=1) m = fmaxf(m, __shfl_xor(m,k,16));
    float s = 0.f;
    #pragma unroll
    for(int g=0;g<16;g++){ float e = __expf(acc[g][r]-m); acc[g][r]=e; s+=e; }
    #pragma unroll
    for(int k=1;k<16;k<<=1) s += __shfl_xor(s,k,16);
    float inv = 1.f/s;
    #pragma unroll
    for(int g=0;g<16;g++) acc[g][r] *= inv;
  }
  long bbase = (long)bh*65536;
  #pragma unroll
  for(int g=0;g<16;g++){
    float ps = 0.f;
    #pragma unroll
    for(int r=0;r<4;r++){
      int row = mt*64 + w*16 + quad*4 + r;
      int col = g*16 + l15;
      float pv = acc[g][r];
      u16 h = f2b(pv);
      ab[bbase + (long)row*256 + col] = h;
      ab[ALOFF + bbase + (long)row*256 + col] = f2b(pv - b2f(h));
      ps += pv;
    }
    ps += __shfl_xor(ps, 16);
    ps += __shfl_xor(ps, 32);
    if(quad==0) atomicAdd(&colsum[bh*256 + g*16 + l15], ps);
  }
}

// ================= pinv init: z0 = a^T / colmax =================
__global__ __launch_bounds__(256) void pinv_init_kernel(const u16* ah, const float* colsum, u16* zh){
  int tile = blockIdx.x, bh = blockIdx.y;
  int tx = tile&3, ty = tile>>2;
  __shared__ u16 th[64][72], tl[64][72];
  __shared__ float red[4];
  int t = threadIdx.x;
  float mc = 0.f;
  for(int i=t;i<4096;i+=256) mc = fmaxf(mc, colsum[i]);
  #pragma unroll
  for(int k=1;k<64;k<<=1) mc = fmaxf(mc, __shfl_xor(mc,k,64));
  if((t&63)==0) red[t>>6]=mc;
  int r = t>>2, c = (t&3)*16;
  const u16* src = ah + (long)bh*65536 + (long)(ty*64 + r)*256 + tx*64 + c;
  *(uint4*)&th[r][c]   = *(const uint4*)src;
  *(uint4*)&th[r][c+8] = *(const uint4*)(src+8);
  *(uint4*)&tl[r][c]   = *(const uint4*)(src+ALOFF);
  *(uint4*)&tl[r][c+8] = *(const uint4*)(src+ALOFF+8);
  __syncthreads();
  float dinv = 1.f/fmaxf(fmaxf(red[0],red[1]), fmaxf(red[2],red[3]));
  u16 oh[16], ol[16];
  #pragma unroll
  for(int jj=0;jj<16;jj++){
    float v = (b2f(th[c+jj][r]) + b2f(tl[c+jj][r])) * dinv;
    u16 h = f2b(v);
    oh[jj] = h; ol[jj] = f2b(v - b2f(h));
  }
  u16* dst = zh + (long)bh*65536 + (long)(tx*64 + r)*256 + ty*64 + c;
  *(uint4*)dst     = *(uint4*)oh;
  *(uint4*)(dst+8) = *(uint4*)(oh+8);
  *(uint4*)(dst+ALOFF)   = *(uint4*)ol;
  *(uint4*)(dst+ALOFF+8) = *(uint4*)(ol+8);
}

// ================= NS full-K LDS GEMM (1 barrier): C = alpha*A@B + beta*I (+dual) =================
struct NS2 { const u16 *A, *B; u16 *Ch, *Cl, *C2h, *C2l; float alpha, beta, alpha2, beta2; };
__global__ __launch_bounds__(256) void ns2_kernel(NS2 p){
  __shared__ u16 Ah[64][264], Al[64][264];
  __shared__ u16 Bt[64][264], Blt[64][264];
  int t = threadIdx.x;
  long boff = (long)blockIdx.z*65536;
  int n0 = blockIdx.x*64, m0 = blockIdx.y*64;
  #pragma unroll
  for(int i=0;i<8;i++){
    int idx = (i*256+t)*8, r = idx>>8, c = idx&255;
    *(uint4*)&Ah[r][c] = *(const uint4*)(p.A + boff + (long)(m0+r)*256 + c);
    *(uint4*)&Al[r][c] = *(const uint4*)(p.A + ALOFF + boff + (long)(m0+r)*256 + c);
  }
  #pragma unroll
  for(int i=0;i<8;i++){
    int idx = (i*256+t)*8, k = idx>>6, n = idx&63;
    u16 th[8], tl[8];
    *(uint4*)th = *(const uint4*)(p.B + boff + (long)k*256 + n0 + n);
    *(uint4*)tl = *(const uint4*)(p.B + ALOFF + boff + (long)k*256 + n0 + n);
    #pragma unroll
    for(int j=0;j<8;j++){ Bt[n+j][k] = th[j]; Blt[n+j][k] = tl[j]; }
  }
  __syncthreads();
  int w = t>>6, lane = t&63, l15 = lane&15, quad = lane>>4;
  f32x4 acc[4];
  #pragma unroll
  for(int i=0;i<4;i++)
    #pragma unroll
    for(int j=0;j<4;j++) acc[i][j]=0.f;
  #pragma unroll
  for(int kk=0; kk<256; kk+=32){
    bh8 a  = *(const bh8*)&Ah[w*16+l15][kk+quad*8];
    bh8 al = *(const bh8*)&Al[w*16+l15][kk+quad*8];
    #pragma unroll
    for(int ct=0; ct<4; ct++){
      bh8 b  = *(const bh8*)&Bt[ct*16+l15][kk+quad*8];
      bh8 bl = *(const bh8*)&Blt[ct*16+l15][kk+quad*8];
      acc[ct] = __builtin_amdgcn_mfma_f32_16x16x32_bf16(a,  b,  acc[ct], 0,0,0);
      acc[ct] = __builtin_amdgcn_mfma_f32_16x16x32_bf16(a,  bl, acc[ct], 0,0,0);
      acc[ct] = __builtin_amdgcn_mfma_f32_16x16x32_bf16(al, b,  acc[ct], 0,0,0);
    }
  }
  #pragma unroll
  for(int ct=0; ct<4; ct++)
    #pragma unroll
    for(int r=0;r<4;r++){
      int col = n0 + ct*16 + l15;
      int row = m0 + w*16 + quad*4 + r;
      long coff = boff + (long)row*256 + col;
      float v = acc[ct][r];
      float v1 = p.alpha*v + ((row==col) ? p.beta : 0.f);
      u16 h = f2b(v1);
      p.Ch[coff] = h;
      p.Cl[coff] = f2b(v1 - b2f(h));
      if(p.C2h){
        float v2 = p.alpha2*v + ((row==col) ? p.beta2 : 0.f);
        u16 h2 = f2b(v2);
        p.C2h[coff] = h2;
        p.C2l[coff] = f2b(v2 - b2f(h2));
      }
    }
}

// ================= NS fused z/y update: {z',y'} = 0.25*{z,y}@t3 ; t1 = 7I - y' =================
struct NSZ { const u16 *zc, *yc, *t3; u16 *zn, *yn, *t1; };
__global__ __launch_bounds__(256) void nsz_kernel(NSZ p){
  __shared__ u16 Ah[64][40], Al[64][40], Bh[64][40], Bl[64][40];
  int t = threadIdx.x;
  int bz = blockIdx.z, half = bz>>4, bh = bz&15;
  long boff = (long)bh*65536;
  int n0 = blockIdx.x*64, m0 = blockIdx.y*64;
  const u16* A = half ? p.yc : p.zc;
  u16* C = half ? p.yn : p.zn;
  int w = t>>6, lane = t&63, l15 = lane&15, quad = lane>>4;
  int ar = t>>2, ac = (t&3)*8;
  int bk = t>>3, bn = (t&7)*8;
  f32x4 acc[4];
  #pragma unroll
  for(int i=0;i<4;i++)
    #pragma unroll
    for(int j=0;j<4;j++) acc[i][j]=0.f;
  for(int kk=0; kk<256; kk+=32){
    __syncthreads();
    *(uint4*)&Ah[ar][ac] = *(const uint4*)(A + boff + (long)(m0+ar)*256 + kk + ac);
    *(uint4*)&Al[ar][ac] = *(const uint4*)(A + ALOFF + boff + (long)(m0+ar)*256 + kk + ac);
    u16 th[8], tl[8];
    *(uint4*)th = *(const uint4*)(p.t3 + boff + (long)(kk+bk)*256 + n0 + bn);
    *(uint4*)tl = *(const uint4*)(p.t3 + ALOFF + boff + (long)(kk+bk)*256 + n0 + bn);
    #pragma unroll
    for(int j=0;j<8;j++){ Bh[bn+j][bk] = th[j]; Bl[bn+j][bk] = tl[j]; }
    __syncthreads();
    bh8 a  = *(const bh8*)&Ah[w*16+l15][quad*8];
    bh8 al = *(const bh8*)&Al[w*16+l15][quad*8];
    #pragma unroll
    for(int ct=0; ct<4; ct++){
      bh8 b  = *(const bh8*)&Bh[ct*16+l15][quad*8];
      bh8 bl = *(const bh8*)&Bl[ct*16+l15][quad*8];
      acc[ct] = __builtin_amdgcn_mfma_f32_16x16x32_bf16(a,  b,  acc[ct], 0,0,0);
      acc[ct] = __builtin_amdgcn_mfma_f32_16x16x32_bf16(a,  bl, acc[ct], 0,0,0);
      acc[ct] = __builtin_amdgcn_mfma_f32_16x16x32_bf16(al, b,  acc[ct], 0,0,0);
    }
  }
  #pragma unroll
  for(int ct=0; ct<4; ct++)
    #pragma unroll
    for(int r=0;r<4;r++){
      int col = n0 + ct*16 + l15;
      int row = m0 + w*16 + quad*4 + r;
      long coff = boff + (long)row*256 + col;
      float v = 0.25f*acc[ct][r];
      u16 h = f2b(v);
      C[coff] = h;
      C[ALOFF + coff] = f2b(v - b2f(h));
      if(half){
        float v2 = ((row==col) ? 7.f : 0.f) - v;
        u16 h2 = f2b(v2);
        p.t1[coff] = h2;
        p.t1[ALOFF + coff] = f2b(v2 - b2f(h2));
      }
    }
}

// ================= W2t = (z @ kv)^T =================
__global__ __launch_bounds__(256) void w2t_kernel(const u16* z, const u16* kvh, u16* w2t){
  __shared__ u16 Ah[64][40], Al[64][40], Bh[64][40], Bl[64][40];
  int t = threadIdx.x;
  int bh = blockIdx.z;
  int m0 = blockIdx.y*64;
  long za = (long)bh*65536;
  long kb = (long)bh*16384;
  int w = t>>6, lane = t&63, l15 = lane&15, quad = lane>>4;
  int ar = t>>2, ac = (t&3)*8;
  int bk = t>>3, bn = (t&7)*8;
  f32x4 acc[4];
  #pragma unroll
  for(int i=0;i<4;i++)
    #pragma unroll
    for(int j=0;j<4;j++) acc[i][j]=0.f;
  for(int kk=0; kk<256; kk+=32){
    __syncthreads();
    *(uint4*)&Ah[ar][ac] = *(const uint4*)(z + za + (long)(m0+ar)*256 + kk + ac);
    *(uint4*)&Al[ar][ac] = *(const uint4*)(z + ALOFF + za + (long)(m0+ar)*256 + kk + ac);
    u16 th[8], tl[8];
    *(uint4*)th = *(const uint4*)(kvh + kb + (long)(kk+bk)*64 + bn);
    *(uint4*)tl = *(const uint4*)(kvh + KVLOFF + kb + (long)(kk+bk)*64 + bn);
    #pragma unroll
    for(int j=0;j<8;j++){ Bh[bn+j][bk] = th[j]; Bl[bn+j][bk] = tl[j]; }
    __syncthreads();
    bh8 a  = *(const bh8*)&Ah[w*16+l15][quad*8];
    bh8 al = *(const bh8*)&Al[w*16+l15][quad*8];
    #pragma unroll
    for(int ct=0; ct<4; ct++){
      bh8 b  = *(const bh8*)&Bh[ct*16+l15][quad*8];
      bh8 bl = *(const bh8*)&Bl[ct*16+l15][quad*8];
      acc[ct] = __builtin_amdgcn_mfma_f32_16x16x32_bf16(a,  b,  acc[ct], 0,0,0);
      acc[ct] = __builtin_amdgcn_mfma_f32_16x16x32_bf16(a,  bl, acc[ct], 0,0,0);
      acc[ct] = __builtin_amdgcn_mfma_f32_16x16x32_bf16(al, b,  acc[ct], 0,0,0);
    }
  }
  #pragma unroll
  for(int ct=0; ct<4; ct++)
    #pragma unroll
    for(int r=0;r<4;r++){
      int col = ct*16 + l15;
      int row = m0 + w*16 + quad*4 + r;
      w2t[kb + (long)col*256 + row] = f2b(acc[ct][r]);
    }
}

// ================= flash sim3+softmax+@v =================
__global__ __launch_bounds__(256) void attn3f_kernel(const u16* ql, const u16* qkv,
                                                     float* opart, float* mpart, float* lpart){
  int s = blockIdx.x, mt = blockIdx.y, bh = blockIdx.z;
  int b = bh>>3, h = bh&7;
  __shared__ u16 qlds[64][72];
  __shared__ u16 Kh[128][72];
  __shared__ u16 Vt[64][136];
  __shared__ u16 plds[64][136];
  int t = threadIdx.x, w = t>>6, lane = t&63, l15 = lane&15, quad = lane>>4;
  {
    int r = t>>2, c = (t&3)*16;
    const u16* src = ql + (long)bh*16384 + (long)(mt*64 + r)*64 + c;
    *(uint4*)&qlds[r][c]   = *(const uint4*)src;
    *(uint4*)&qlds[r][c+8] = *(const uint4*)(src+8);
  }
  float mrun[4], lrun[4];
  #pragma unroll
  for(int r=0;r<4;r++){ mrun[r] = -3.0e38f; lrun[r] = 0.f; }
  f32x4 O[4];
  #pragma unroll
  for(int i=0;i<4;i++)
    #pragma unroll
    for(int j=0;j<4;j++) O[i][j]=0.f;

  for(int ch=0; ch<8; ch++){
    long n0 = (long)s*1024 + ch*128;
    __syncthreads();
    #pragma unroll
    for(int pss=0; pss<4; pss++){
      int r = pss*32 + (t>>3), c = (t&7)*8;
      const u16* ksrc = qkv + 512 + ((long)b*NSEQ + n0 + r)*1536 + h*64 + c;
      *(uint4*)&Kh[r][c] = *(const uint4*)ksrc;
      u16 tv[8];
      *(uint4*)tv = *(const uint4*)(ksrc + 512);
      #pragma unroll
      for(int j=0;j<8;j++) Vt[c+j][r] = tv[j];
    }
    __syncthreads();
    f32x4 sc[8];
    #pragma unroll
    for(int i=0;i<8;i++)
      #pragma unroll
      for(int j=0;j<4;j++) sc[i][j]=0.f;
    #pragma unroll
    for(int g=0; g<8; g++)
      #pragma unroll
      for(int kk=0; kk<64; kk+=32){
        bh8 a  = *(const bh8*)&qlds[w*16+l15][kk+quad*8];
        bh8 bb = *(const bh8*)&Kh[g*16+l15][kk+quad*8];
        sc[g] = __builtin_amdgcn_mfma_f32_16x16x32_bf16(a, bb, sc[g], 0,0,0);
      }
    #pragma unroll
    for(int r=0;r<4;r++){
      float cm = -3.0e38f;
      #pragma unroll
      for(int g=0;g<8;g++) cm = fmaxf(cm, sc[g][r]);
      #pragma unroll
      for(int k=1;k<16;k<<=1) cm = fmaxf(cm, __shfl_xor(cm,k,16));
      float nm = fmaxf(mrun[r], cm);
      float alpha = __expf(mrun[r]-nm);
      mrun[r] = nm;
      float psum = 0.f;
      #pragma unroll
      for(int g=0;g<8;g++){ float e = __expf(sc[g][r]-nm); sc[g][r]=e; psum+=e; }
      #pragma unroll
      for(int k=1;k<16;k<<=1) psum += __shfl_xor(psum,k,16);
      lrun[r] = lrun[r]*alpha + psum;
      #pragma unroll
      for(int ct=0;ct<4;ct++) O[ct][r] *= alpha;
    }
    #pragma unroll
    for(int g=0;g<8;g++)
      #pragma unroll
      for(int r=0;r<4;r++)
        plds[w*16 + quad*4 + r][g*16 + l15] = f2b(sc[g][r]);
    __syncthreads();
    #pragma unroll
    for(int kk=0; kk<128; kk+=32){
      bh8 a = *(const bh8*)&plds[w*16+l15][kk+quad*8];
      #pragma unroll
      for(int ct=0; ct<4; ct++){
        bh8 bb = *(const bh8*)&Vt[ct*16+l15][kk+quad*8];
        O[ct] = __builtin_amdgcn_mfma_f32_16x16x32_bf16(a, bb, O[ct], 0,0,0);
      }
    }
  }
  long rbase = (long)(s*16 + bh)*256 + mt*64 + w*16;
  #pragma unroll
  for(int ct=0; ct<4; ct++)
    #pragma unroll
    for(int r=0;r<4;r++)
      opart[(rbase + quad*4 + r)*64 + ct*16 + l15] = O[ct][r];
  if(l15==0){
    #pragma unroll
    for(int r=0;r<4;r++){
      mpart[rbase + quad*4 + r] = mrun[r];
      lpart[rbase + quad*4 + r] = lrun[r];
    }
  }
}

// ================= combine flash partials -> kv hilo =================
__global__ __launch_bounds__(256) void kvcomb_kernel(const float* opart, const float* mpart,
                                                     const float* lpart, u16* kvh){
  long i = (long)blockIdx.x*256 + threadIdx.x;
  int col = (int)(i & 63);
  long rb = i >> 6;
  float M = -3.0e38f;
  #pragma unroll
  for(int s=0;s<NSPLIT;s++) M = fmaxf(M, mpart[(long)s*4096 + rb]);
  float num = 0.f, den = 0.f;
  #pragma unroll
  for(int s=0;s<NSPLIT;s++){
    float e = __expf(mpart[(long)s*4096 + rb] - M);
    den += e * lpart[(long)s*4096 + rb];
    num += e * opart[((long)s*4096 + rb)*64 + col];
  }
  float v = num/den;
  u16 h = f2b(v);
  kvh[i] = h;
  kvh[KVLOFF + i] = f2b(v - b2f(h));
}

// ================= fused attn1 + conv residual -> oh2 =================
__global__ __launch_bounds__(256) void attn1c_kernel(const u16* qkv, const u16* kl,
                                                     const u16* w2t, const u16* cw, u16* oh2){
  int bh = blockIdx.y, b = bh>>3, h = bh&7;
  int n0 = blockIdx.x*64;
  __shared__ u16 qlds[64][72];
  __shared__ u16 klds[64][72];
  __shared__ u16 plds[64][264];
  __shared__ u16 w2lds[64][72];
  __shared__ u16 vlds[96][72];
  __shared__ float wsh[33];
  int t = threadIdx.x, w = t>>6, lane = t&63, l15 = lane&15, quad = lane>>4;
  if(t<33) wsh[t] = b2f(cw[h*33 + t]);
  {
    int r = t>>2, c = (t&3)*16;
    const u16* src = qkv + ((long)b*NSEQ + n0 + r)*1536 + h*64 + c;
    *(uint4*)&qlds[r][c]   = *(const uint4*)src;
    *(uint4*)&qlds[r][c+8] = *(const uint4*)(src+8);
  }
  // v halo: rows n0-16 .. n0+79
  #pragma unroll
  for(int i=0;i<3;i++){
    int idx = i*256 + t;
    int r = idx>>3, c = (idx&7)*8;
    int n = n0 - 16 + r;
    if(n>=0 && n<NSEQ){
      *(uint4*)&vlds[r][c] = *(const uint4*)(qkv + ((long)b*NSEQ + n)*1536 + 1024 + h*64 + c);
    } else {
      uint4 zz; zz.x=zz.y=zz.z=zz.w=0u;
      *(uint4*)&vlds[r][c] = zz;
    }
  }
  f32x4 acc[16];
  #pragma unroll
  for(int i=0;i<16;i++)
    #pragma unroll
    for(int j=0;j<4;j++) acc[i][j]=0.f;
  const u16* klb = kl + (long)bh*16384;
  for(int nt=0; nt<4; nt++){
    __syncthreads();
    {
      int r = t>>2, c = (t&3)*16;
      const u16* src = klb + (long)(nt*64 + r)*64 + c;
      *(uint4*)&klds[r][c]   = *(const uint4*)src;
      *(uint4*)&klds[r][c+8] = *(const uint4*)(src+8);
    }
    __syncthreads();
    #pragma unroll
    for(int kk=0; kk<64; kk+=32){
      bh8 a = *(const bh8*)&qlds[w*16+l15][kk+quad*8];
      #pragma unroll
      for(int ct=0; ct<4; ct++){
        bh8 bb = *(const bh8*)&klds[ct*16+l15][kk+quad*8];
        acc[nt*4+ct] = __builtin_amdgcn_mfma_f32_16x16x32_bf16(a, bb, acc[nt*4+ct], 0,0,0);
      }
    }
  }
  float linv[4];
  #pragma unroll
  for(int g=0; g<16; g++)
    #pragma unroll
    for(int r=0;r<4;r++) acc[g][r] *= 0.125f;
  #pragma unroll
  for(int r=0;r<4;r++){
    float m = -3.0e38f;
    #pragma unroll
    for(int g=0;g<16;g++) m = fmaxf(m, acc[g][r]);
    #pragma unroll
    for(int k=1;k<16;k<<=1) m = fmaxf(m, __shfl_xor(m,k,16));
    float s = 0.f;
    #pragma unroll
    for(int g=0;g<16;g++){ float e = __expf(acc[g][r]-m); acc[g][r]=e; s+=e; }
    #pragma unroll
    for(int k=1;k<16;k<<=1) s += __shfl_xor(s,k,16);
    linv[r] = 1.f/s;
  }
  #pragma unroll
  for(int g=0;g<16;g++)
    #pragma unroll
    for(int r=0;r<4;r++)
      plds[w*16 + quad*4 + r][g*16 + l15] = f2b(acc[g][r]*linv[r]);
  f32x4 acc2[4];
  #pragma unroll
  for(int i=0;i<4;i++)
    #pragma unroll
    for(int j=0;j<4;j++) acc2[i][j]=0.f;
  const u16* w2b = w2t + (long)bh*16384;
  for(int kc=0; kc<4; kc++){
    __syncthreads();
    {
      int r = t>>2, c = (t&3)*16;
      const u16* src = w2b + (long)r*256 + kc*64 + c;
      *(uint4*)&w2lds[r][c]   = *(const uint4*)src;
      *(uint4*)&w2lds[r][c+8] = *(const uint4*)(src+8);
    }
    __syncthreads();
    #pragma unroll
    for(int kk=0; kk<64; kk+=32){
      bh8 a = *(const bh8*)&plds[w*16+l15][kc*64+kk+quad*8];
      #pragma unroll
      for(int ct=0; ct<4; ct++){
        bh8 bb = *(const bh8*)&w2lds[ct*16+l15][kk+quad*8];
        acc2[ct] = __builtin_amdgcn_mfma_f32_16x16x32_bf16(a, bb, acc2[ct], 0,0,0);
      }
    }
  }
  // epilogue: + depthwise conv from vlds
  #pragma unroll
  for(int ct=0; ct<4; ct++)
    #pragma unroll
    for(int r=0;r<4;r++){
      int nloc = w*16 + quad*4 + r;
      int d = ct*16 + l15;
      float s = 0.f;
      #pragma unroll
      for(int j=0;j<33;j++) s += b2f(vlds[nloc+j][d]) * wsh[j];
      oh2[((long)b*NSEQ + n0 + nloc)*512 + h*64 + d] = f2b(acc2[ct][r] + s);
    }
}

// ================= host =================
extern "C" void kernel_launch(void* const* d_in, const int* in_sizes, int n_in,
                              void* d_out, int out_size, void* d_ws, size_t ws_size,
                              hipStream_t stream){
  char* wsp = (char*)d_ws;
  size_t off = 0;
  auto alloc = [&](size_t bytes)->char*{
    char* p = wsp + off; off = (off + bytes + 255) & ~(size_t)255; return p;
  };
  u16* gb   = (u16*)alloc(1024);
  u16* bb   = (u16*)alloc(1024);
  u16* bob  = (u16*)alloc(1024);
  u16* cwb  = (u16*)alloc(1024);
  u16* wqt  = (u16*)alloc(1572864);
  u16* wot  = (u16*)alloc(524288);
  unsigned* flag = (unsigned*)alloc(256);
  float* colsum = (float*)alloc(16384);
  u16*   xn   = (u16*)alloc(16777216);
  u16*   qkv  = (u16*)alloc(50331648);
  u16*   ql   = (u16*)alloc(524288);
  u16*   kl   = (u16*)alloc(524288);
  u16*   ab   = (u16*)alloc(4194304);     // attn2 hilo
  u16*   zA   = (u16*)alloc(4194304);
  u16*   zB   = (u16*)alloc(4194304);
  u16*   yA   = (u16*)alloc(4194304);
  u16*   yB   = (u16*)alloc(4194304);
  u16*   t1b  = (u16*)alloc(4194304);
  u16*   t2b  = (u16*)alloc(4194304);
  u16*   t3b  = (u16*)alloc(4194304);
  u16*   kvb  = (u16*)alloc(1048576);
  u16*   w2t  = (u16*)alloc(524288);
  u16*   oh2  = (u16*)alloc(16777216);
  float* opart= (float*)alloc(8388608);
  float* mpart= (float*)alloc(131072);
  float* lpart= (float*)alloc(131072);

  // 1. setup
  setup_kernel<<<dim3(1024), 256, 0, stream>>>(d_in[1], d_in[2], d_in[5], d_in[6],
                                               d_in[3], d_in[4],
                                               gb, bb, bob, cwb, wqt, wot, flag, colsum);
  // 2. LayerNorm
  ln_kernel<<<dim3(16384), 256, 0, stream>>>(d_in[0], flag, gb, bb, xn);
  // 3. qkv = xn @ W_qkv
  { G128 p{}; p.A=xn; p.Bt=wqt; p.C=qkv; p.lda=512; p.ldb=512; p.ldc=1536; p.K=512;
    gemm128_kernel<<<dim3(12,128,1), 256, 0, stream>>>(p); }
  // 4. landmarks
  landmark_kernel<<<dim3(256,16), dim3(64), 0, stream>>>(qkv, ql, kl);
  // 5. sim2 + softmax + colsum
  sim2_kernel<<<dim3(4,16), 256, 0, stream>>>(ql, kl, ab, colsum);
  // 6. pinv init -> z0
  pinv_init_kernel<<<dim3(16,16), 256, 0, stream>>>(ab, colsum, zA);
  // 7. NS with y-carry: y0 = a@z0 (dual t1 = 7I - y0), then 6 x 3 launches
  { NS2 q{ab, zA, yA, yA+ALOFF, t1b, t1b+ALOFF, 1.f, 0.f, -1.f, 7.f};
    ns2_kernel<<<dim3(4,4,16), 256, 0, stream>>>(q); }
  u16 *zc=zA, *zn=zB, *yc=yA, *yn=yB;
  for(int it=0; it<6; it++){
    { NS2 q{yc, t1b, t2b, t2b+ALOFF, nullptr, nullptr, -1.f, 15.f, 0.f, 0.f};
      ns2_kernel<<<dim3(4,4,16), 256, 0, stream>>>(q); }
    { NS2 q{yc, t2b, t3b, t3b+ALOFF, nullptr, nullptr, -1.f, 13.f, 0.f, 0.f};
      ns2_kernel<<<dim3(4,4,16), 256, 0, stream>>>(q); }
    { NSZ q{zc, yc, t3b, zn, yn, t1b};
      nsz_kernel<<<dim3(4,4,32), 256, 0, stream>>>(q); }
    u16* tz=zc; zc=zn; zn=tz;
    u16* ty=yc; yc=yn; yn=ty;
  }
  // 8. flash sim3+softmax+@v
  attn3f_kernel<<<dim3(NSPLIT,4,16), 256, 0, stream>>>(ql, qkv, opart, mpart, lpart);
  // 9. combine -> kv hilo
  kvcomb_kernel<<<dim3(1024), 256, 0, stream>>>(opart, mpart, lpart, kvb);
  // 10. W2t = (z @ kv)^T
  w2t_kernel<<<dim3(1,4,16), 256, 0, stream>>>(zc, kvb, w2t);
  // 11. fused attn1 + conv -> oh2
  attn1c_kernel<<<dim3(128,16), 256, 0, stream>>>(qkv, kl, w2t, cwb, oh2);
  // 12. final: out = oh2 @ W_out + b_out + xn
  { G128 p{}; p.A=oh2; p.Bt=wot; p.C=(u16*)d_out; p.bias=bob; p.resid=xn; p.oflag=flag;
    p.lda=512; p.ldb=512; p.ldc=512; p.ldr=512; p.K=512;
    gemm128_kernel<<<dim3(4,128,1), 256, 0, stream>>>(p); }
}